// Round 1
// baseline (1272.913 us; speedup 1.0000x reference)
//
#include <hip/hip_runtime.h>
#include <math.h>

#define BB 64
#define NN 512
#define NH 4
#define FI 16
#define FO 64
#define HD1 1024
#define HD2 512
#define ODIM 40

#define IT 64   // rows per attn block
#define JT 32   // j tile

// ---------------- kernel 1: per-node projection, attn scalars, skip+bias ----------------
__global__ __launch_bounds__(256) void k_proj(
    const float* __restrict__ x, const float* __restrict__ w,
    const float* __restrict__ a_src, const float* __restrict__ a_dst,
    const float* __restrict__ bias,
    float* __restrict__ hp, float* __restrict__ asrc, float* __restrict__ adst,
    float* __restrict__ gat)
{
    int bn = blockIdx.x;
    int b = bn >> 9, n = bn & (NN - 1);
    __shared__ float node[FI];
    __shared__ float hpl[NH][FO];
    int t = threadIdx.x;
    if (t < FI) node[t] = x[bn * FI + t];
    __syncthreads();
    int h = t >> 6, o = t & 63;
    float acc = 0.f;
#pragma unroll
    for (int i = 0; i < FI; ++i)
        acc = fmaf(node[i], w[(h * FI + i) * FO + o], acc);
    hp[((b * NH + h) * NN + n) * FO + o] = acc;
    hpl[h][o] = acc;
    float vs = acc * a_src[h * FO + o];
    float vd = acc * a_dst[h * FO + o];
#pragma unroll
    for (int off = 32; off; off >>= 1) {
        vs += __shfl_down(vs, off);
        vd += __shfl_down(vd, off);
    }
    if (o == 0) {
        asrc[(b * NH + h) * NN + n] = vs;
        adst[(b * NH + h) * NN + n] = vd;
    }
    __syncthreads();
    if (t < FO) {
        float s = bias[t];
#pragma unroll
        for (int hh = 0; hh < NH; ++hh) s += hpl[hh][t];
        gat[bn * FO + t] = s;   // bias + skip (sum over heads); attn PV added later
    }
}

// ---------------- kernel 2: per-row softmax stats (max, 1/sumexp) ----------------
__global__ __launch_bounds__(256) void k_stats(
    const float* __restrict__ asrc, const float* __restrict__ adst,
    float* __restrict__ rm, float* __restrict__ rr)
{
    int bh = blockIdx.x;              // b*NH + h
    __shared__ float d[NN];
    int t = threadIdx.x;
    for (int j = t; j < NN; j += 256) d[j] = adst[bh * NN + j];
    __syncthreads();
    for (int i = t; i < NN; i += 256) {
        float s = asrc[bh * NN + i];
        float m = -INFINITY;
        for (int j = 0; j < NN; ++j) {
            float v = s * d[j];
            v = v >= 0.f ? v : 0.2f * v;
            m = fmaxf(m, v);
        }
        float sum = 0.f;
        for (int j = 0; j < NN; ++j) {
            float v = s * d[j];
            v = v >= 0.f ? v : 0.2f * v;
            sum += __expf(v - m);
        }
        rm[bh * NN + i] = m;
        rr[bh * NN + i] = 1.0f / sum;   // softmax denominator includes ALL j (mask applied after)
    }
}

// ---------------- kernel 3: softmax weights (recomputed) * mask, PV, head-sum ----------------
__global__ __launch_bounds__(256) void k_attn(
    const float* __restrict__ hp, const float* __restrict__ mask,
    const float* __restrict__ asrc, const float* __restrict__ adst,
    const float* __restrict__ rm, const float* __restrict__ rr,
    float* __restrict__ gat)
{
    __shared__ float smem[NH*JT*FO + NH*IT*(JT+1) + 3*NH*IT + NH*JT]; // ~70 KiB
    float* hpT = smem;                        // [NH*JT][FO]
    float* wgt = smem + NH*JT*FO;             // [(h*IT+i)*(JT+1)+j], +1 pad kills bank conflicts
    float* sS  = wgt + NH*IT*(JT+1);
    float* mS  = sS + NH*IT;
    float* rS  = mS + NH*IT;
    float* dS  = rS + NH*IT;                  // [NH][JT]
    float* outS = smem;                       // aliases hpT after the main loop

    int b = blockIdx.y;
    int i0blk = blockIdx.x * IT;
    int t = threadIdx.x;
    {
        int h = t >> 6, i = t & 63;
        int idx = (b*NH + h)*NN + i0blk + i;
        sS[h*IT + i] = asrc[idx];
        mS[h*IT + i] = rm[idx];
        rS[h*IT + i] = rr[idx];
    }
    const int ht = t >> 6;           // wave index == head
    const int u  = t & 63;
    const int i0 = (u >> 2) * 4;     // 4-row sub-tile
    const int oc = (u & 3) * 16;     // 16-col sub-tile
    float acc[4][16];
#pragma unroll
    for (int r = 0; r < 4; ++r)
#pragma unroll
        for (int c = 0; c < 16; ++c) acc[r][c] = 0.f;

    for (int jt = 0; jt < NN/JT; ++jt) {
        __syncthreads();
        if (t < NH*JT) {
            int h = t >> 5, jj = t & 31;
            dS[t] = adst[(b*NH + h)*NN + jt*JT + jj];
        }
#pragma unroll
        for (int k = 0; k < 8; ++k) {          // stage hp tile [4 heads][32 j][64 o]
            int idx = t + k*256;
            int row = idx >> 4;
            int c4  = idx & 15;
            int h = row >> 5, jj = row & 31;
            float4 v = *(const float4*)&hp[(((b*NH + h)*NN) + jt*JT + jj)*FO + c4*4];
            *(float4*)&hpT[row*FO + c4*4] = v;
        }
        __syncthreads();
#pragma unroll
        for (int k = 0; k < 32; ++k) {         // weights = exp(l - m) * r * mask
            int idx = t + k*256;
            int j = idx & 31;
            int i = (idx >> 5) & 63;
            int h = idx >> 11;
            float sv = sS[h*IT + i];
            float v = sv * dS[h*JT + j];
            v = v >= 0.f ? v : 0.2f * v;
            float e = __expf(v - mS[h*IT + i]) * rS[h*IT + i];
            float mk = mask[((size_t)b*NN + i0blk + i)*NN + jt*JT + j];
            wgt[(h*IT + i)*(JT+1) + j] = e * mk;
        }
        __syncthreads();
#pragma unroll 4
        for (int jj = 0; jj < JT; ++jj) {
            float wv[4];
#pragma unroll
            for (int r = 0; r < 4; ++r)
                wv[r] = wgt[(ht*IT + i0 + r)*(JT+1) + jj];
            float hv[16];
#pragma unroll
            for (int c4 = 0; c4 < 4; ++c4) {
                float4 v = *(const float4*)&hpT[(ht*JT + jj)*FO + oc + c4*4];
                hv[c4*4+0] = v.x; hv[c4*4+1] = v.y; hv[c4*4+2] = v.z; hv[c4*4+3] = v.w;
            }
#pragma unroll
            for (int r = 0; r < 4; ++r)
#pragma unroll
                for (int c = 0; c < 16; ++c)
                    acc[r][c] = fmaf(wv[r], hv[c], acc[r][c]);
        }
    }
    __syncthreads();
    // reduce partial PV over the 4 heads (one wave each) in LDS
    for (int hh = 0; hh < NH; ++hh) {
        if (ht == hh) {
#pragma unroll
            for (int r = 0; r < 4; ++r)
#pragma unroll
                for (int c = 0; c < 16; ++c) {
                    if (hh == 0) outS[(i0+r)*FO + oc + c] = acc[r][c];
                    else         outS[(i0+r)*FO + oc + c] += acc[r][c];
                }
        }
        __syncthreads();
    }
#pragma unroll
    for (int k = 0; k < 4; ++k) {
        int idx4 = t + k*256;
        int i = idx4 >> 4;
        int c4 = idx4 & 15;
        int g = (b*NN + i0blk + i)*FO + c4*4;
        float4 base = *(const float4*)&gat[g];
        float4 v = *(float4*)&outS[i*FO + c4*4];
        v.x += base.x; v.y += base.y; v.z += base.z; v.w += base.w;
        *(float4*)&gat[g] = v;
    }
}

// ---------------- kernel 4: fused MLP (relu -> W1 -> relu -> W2 -> relu -> W3 -> sigmoid/clip) ----------------
__global__ __launch_bounds__(256) void k_mlp(
    const float* __restrict__ gat,
    const float* __restrict__ W1, const float* __restrict__ b1,
    const float* __restrict__ W2, const float* __restrict__ b2,
    const float* __restrict__ W3, const float* __restrict__ b3,
    float* __restrict__ out)
{
    __shared__ float inT[FO][16];        // [k][r], relu applied
    __shared__ float h1T[HD1][20];       // [k][r], pad 16->20 (80B rows, 16B aligned)
    __shared__ float h2s[16][516];       // [r][k], pad 512->516, relu applied
    int t = threadIdx.x;
    size_t row0 = (size_t)blockIdx.x * 16;
    {
        float4 v = *(const float4*)&gat[row0*FO + t*4];
        int r = t >> 4, k0 = (t & 15) * 4;
        inT[k0+0][r] = fmaxf(v.x, 0.f);
        inT[k0+1][r] = fmaxf(v.y, 0.f);
        inT[k0+2][r] = fmaxf(v.z, 0.f);
        inT[k0+3][r] = fmaxf(v.w, 0.f);
    }
    __syncthreads();
    // GEMM1: [16 x 64] @ [64 x 1024]; thread owns 4 cols x 16 rows
    float acc1[4][16];
#pragma unroll
    for (int c = 0; c < 4; ++c)
#pragma unroll
        for (int r = 0; r < 16; ++r) acc1[c][r] = 0.f;
    for (int k = 0; k < FO; ++k) {
        float in16[16];
#pragma unroll
        for (int q = 0; q < 4; ++q) {
            float4 v = *(const float4*)&inT[k][q*4];
            in16[q*4+0] = v.x; in16[q*4+1] = v.y; in16[q*4+2] = v.z; in16[q*4+3] = v.w;
        }
#pragma unroll
        for (int c = 0; c < 4; ++c) {
            float wv = W1[k*HD1 + t + c*256];
#pragma unroll
            for (int r = 0; r < 16; ++r)
                acc1[c][r] = fmaf(wv, in16[r], acc1[c][r]);
        }
    }
#pragma unroll
    for (int c = 0; c < 4; ++c) {
        int o = t + c*256;
        float bb = b1[o];
#pragma unroll
        for (int r4 = 0; r4 < 4; ++r4) {
            float4 p;
            p.x = fmaxf(acc1[c][r4*4+0] + bb, 0.f);
            p.y = fmaxf(acc1[c][r4*4+1] + bb, 0.f);
            p.z = fmaxf(acc1[c][r4*4+2] + bb, 0.f);
            p.w = fmaxf(acc1[c][r4*4+3] + bb, 0.f);
            *(float4*)&h1T[o][r4*4] = p;
        }
    }
    __syncthreads();
    // GEMM2: [16 x 1024] @ [1024 x 512]; thread owns 4 cols x 8 rows
    int rh = t >> 7, cg = t & 127;
    int o0 = cg*4, r0 = rh*8;
    float acc2[4][8];
#pragma unroll
    for (int c = 0; c < 4; ++c)
#pragma unroll
        for (int r = 0; r < 8; ++r) acc2[c][r] = 0.f;
#pragma unroll 4
    for (int k = 0; k < HD1; ++k) {
        float4 va = *(const float4*)&h1T[k][r0];
        float4 vb = *(const float4*)&h1T[k][r0+4];
        float h8[8] = {va.x, va.y, va.z, va.w, vb.x, vb.y, vb.z, vb.w};
        float4 wv = *(const float4*)&W2[k*HD2 + o0];
        float w4[4] = {wv.x, wv.y, wv.z, wv.w};
#pragma unroll
        for (int c = 0; c < 4; ++c)
#pragma unroll
            for (int r = 0; r < 8; ++r)
                acc2[c][r] = fmaf(w4[c], h8[r], acc2[c][r]);
    }
    {
        float bb0 = b2[o0+0], bb1 = b2[o0+1], bb2v = b2[o0+2], bb3v = b2[o0+3];
#pragma unroll
        for (int r = 0; r < 8; ++r) {
            float4 v;
            v.x = fmaxf(acc2[0][r] + bb0, 0.f);
            v.y = fmaxf(acc2[1][r] + bb1, 0.f);
            v.z = fmaxf(acc2[2][r] + bb2v, 0.f);
            v.w = fmaxf(acc2[3][r] + bb3v, 0.f);
            *(float4*)&h2s[r0+r][o0] = v;
        }
    }
    __syncthreads();
    // GEMM3: [16 x 512] @ [512 x 40], sigmoid + clip
#pragma unroll
    for (int q = 0; q < 3; ++q) {
        int idx = t + q*256;
        if (idx < 16*ODIM) {
            int r = idx / ODIM, o = idx - r*ODIM;
            float acc = b3[o];
            for (int k = 0; k < HD2; k += 4) {
                float4 v = *(const float4*)&h2s[r][k];
                acc = fmaf(v.x, W3[(k+0)*ODIM + o], acc);
                acc = fmaf(v.y, W3[(k+1)*ODIM + o], acc);
                acc = fmaf(v.z, W3[(k+2)*ODIM + o], acc);
                acc = fmaf(v.w, W3[(k+3)*ODIM + o], acc);
            }
            float s = 1.f / (1.f + __expf(-acc));
            s = fminf(fmaxf(s, 0.01f), 0.99f);
            out[(row0 + r)*ODIM + o] = s;
        }
    }
}

extern "C" void kernel_launch(void* const* d_in, const int* in_sizes, int n_in,
                              void* d_out, int out_size, void* d_ws, size_t ws_size,
                              hipStream_t stream)
{
    const float* x     = (const float*)d_in[0];
    const float* mask  = (const float*)d_in[1];
    const float* w     = (const float*)d_in[2];
    const float* a_src = (const float*)d_in[3];
    const float* a_dst = (const float*)d_in[4];
    const float* bias  = (const float*)d_in[5];
    const float* W1    = (const float*)d_in[6];
    const float* b1    = (const float*)d_in[7];
    const float* W2    = (const float*)d_in[8];
    const float* b2    = (const float*)d_in[9];
    const float* W3    = (const float*)d_in[10];
    const float* b3    = (const float*)d_in[11];
    float* out = (float*)d_out;

    float* ws   = (float*)d_ws;
    float* hp   = ws;                                   // [B][H][N][64]  (32 MiB)
    float* asrc = hp   + (size_t)BB*NH*NN*FO;
    float* adst = asrc + (size_t)BB*NH*NN;
    float* rm   = adst + (size_t)BB*NH*NN;
    float* rr   = rm   + (size_t)BB*NH*NN;
    float* gat  = rr   + (size_t)BB*NH*NN;              // [B][N][64]  (8 MiB)

    k_proj <<<BB*NN, 256, 0, stream>>>(x, w, a_src, a_dst, bias, hp, asrc, adst, gat);
    k_stats<<<BB*NH, 256, 0, stream>>>(asrc, adst, rm, rr);
    k_attn <<<dim3(NN/IT, BB), 256, 0, stream>>>(hp, mask, asrc, adst, rm, rr, gat);
    k_mlp  <<<BB*NN/16, 256, 0, stream>>>(gat, W1, b1, W2, b2, W3, b3, out);
}

// Round 2
// 672.812 us; speedup vs baseline: 1.8919x; 1.8919x over previous
//
#include <hip/hip_runtime.h>
#include <math.h>

typedef short bf16x8 __attribute__((ext_vector_type(8)));
typedef float f32x4 __attribute__((ext_vector_type(4)));

#define BB 64
#define NN 512
#define NH 4
#define FI 16
#define FO 64
#define HD1 1024
#define HD2 512
#define ODIM 40

#define IT 64   // rows per attn block
#define JT 32   // j tile

__device__ __forceinline__ unsigned short f2bf(float f) {
    unsigned u = __float_as_uint(f);
    u += 0x7fffu + ((u >> 16) & 1u);        // RNE
    return (unsigned short)(u >> 16);
}
__device__ __forceinline__ unsigned pack2(float a, float b) {
    return (unsigned)f2bf(a) | ((unsigned)f2bf(b) << 16);
}

// ---------------- kernel 1: per-node projection, attn scalars, skip+bias ----------------
__global__ __launch_bounds__(256) void k_proj(
    const float* __restrict__ x, const float* __restrict__ w,
    const float* __restrict__ a_src, const float* __restrict__ a_dst,
    const float* __restrict__ bias,
    float* __restrict__ hp, float* __restrict__ asrc, float* __restrict__ adst,
    float* __restrict__ gat)
{
    int bn = blockIdx.x;
    int b = bn >> 9, n = bn & (NN - 1);
    __shared__ float node[FI];
    __shared__ float hpl[NH][FO];
    int t = threadIdx.x;
    if (t < FI) node[t] = x[bn * FI + t];
    __syncthreads();
    int h = t >> 6, o = t & 63;
    float acc = 0.f;
#pragma unroll
    for (int i = 0; i < FI; ++i)
        acc = fmaf(node[i], w[(h * FI + i) * FO + o], acc);
    hp[((b * NH + h) * NN + n) * FO + o] = acc;
    hpl[h][o] = acc;
    float vs = acc * a_src[h * FO + o];
    float vd = acc * a_dst[h * FO + o];
#pragma unroll
    for (int off = 32; off; off >>= 1) {
        vs += __shfl_down(vs, off);
        vd += __shfl_down(vd, off);
    }
    if (o == 0) {
        asrc[(b * NH + h) * NN + n] = vs;
        adst[(b * NH + h) * NN + n] = vd;
    }
    __syncthreads();
    if (t < FO) {
        float s = bias[t];
#pragma unroll
        for (int hh = 0; hh < NH; ++hh) s += hpl[hh][t];
        gat[bn * FO + t] = s;   // bias + skip (sum over heads); attn PV added later
    }
}

// ---------------- kernel 2: per-row softmax stats (max, 1/sumexp) ----------------
__global__ __launch_bounds__(256) void k_stats(
    const float* __restrict__ asrc, const float* __restrict__ adst,
    float* __restrict__ rm, float* __restrict__ rr)
{
    int bh = blockIdx.x;              // b*NH + h
    __shared__ float d[NN];
    int t = threadIdx.x;
    for (int j = t; j < NN; j += 256) d[j] = adst[bh * NN + j];
    __syncthreads();
    for (int i = t; i < NN; i += 256) {
        float s = asrc[bh * NN + i];
        float m = -INFINITY;
        for (int j = 0; j < NN; ++j) {
            float v = s * d[j];
            v = v >= 0.f ? v : 0.2f * v;
            m = fmaxf(m, v);
        }
        float sum = 0.f;
        for (int j = 0; j < NN; ++j) {
            float v = s * d[j];
            v = v >= 0.f ? v : 0.2f * v;
            sum += __expf(v - m);
        }
        rm[bh * NN + i] = m;
        rr[bh * NN + i] = 1.0f / sum;   // softmax denominator includes ALL j (mask applied after)
    }
}

// ---------------- kernel 3: softmax weights (recomputed) * mask, PV, head-sum ----------------
__global__ __launch_bounds__(256) void k_attn(
    const float* __restrict__ hp, const float* __restrict__ mask,
    const float* __restrict__ asrc, const float* __restrict__ adst,
    const float* __restrict__ rm, const float* __restrict__ rr,
    float* __restrict__ gat)
{
    __shared__ float smem[NH*JT*FO + NH*IT*(JT+1) + 3*NH*IT + NH*JT]; // ~70 KiB
    float* hpT = smem;                        // [NH*JT][FO]
    float* wgt = smem + NH*JT*FO;             // [(h*IT+i)*(JT+1)+j]
    float* sS  = wgt + NH*IT*(JT+1);
    float* mS  = sS + NH*IT;
    float* rS  = mS + NH*IT;
    float* dS  = rS + NH*IT;                  // [NH][JT]
    float* outS = smem;                       // aliases hpT after the main loop

    int b = blockIdx.y;
    int i0blk = blockIdx.x * IT;
    int t = threadIdx.x;
    {
        int h = t >> 6, i = t & 63;
        int idx = (b*NH + h)*NN + i0blk + i;
        sS[h*IT + i] = asrc[idx];
        mS[h*IT + i] = rm[idx];
        rS[h*IT + i] = rr[idx];
    }
    const int ht = t >> 6;           // wave index == head
    const int u  = t & 63;
    const int i0 = (u >> 2) * 4;     // 4-row sub-tile
    const int oc = (u & 3) * 16;     // 16-col sub-tile
    float acc[4][16];
#pragma unroll
    for (int r = 0; r < 4; ++r)
#pragma unroll
        for (int c = 0; c < 16; ++c) acc[r][c] = 0.f;

    for (int jt = 0; jt < NN/JT; ++jt) {
        __syncthreads();
        if (t < NH*JT) {
            int h = t >> 5, jj = t & 31;
            dS[t] = adst[(b*NH + h)*NN + jt*JT + jj];
        }
#pragma unroll
        for (int k = 0; k < 8; ++k) {          // stage hp tile [4 heads][32 j][64 o]
            int idx = t + k*256;
            int row = idx >> 4;
            int c4  = idx & 15;
            int h = row >> 5, jj = row & 31;
            float4 v = *(const float4*)&hp[(((b*NH + h)*NN) + jt*JT + jj)*FO + c4*4];
            *(float4*)&hpT[row*FO + c4*4] = v;
        }
        __syncthreads();
#pragma unroll
        for (int k = 0; k < 32; ++k) {         // weights = exp(l - m) * r * mask
            int idx = t + k*256;
            int j = idx & 31;
            int i = (idx >> 5) & 63;
            int h = idx >> 11;
            float sv = sS[h*IT + i];
            float v = sv * dS[h*JT + j];
            v = v >= 0.f ? v : 0.2f * v;
            float e = __expf(v - mS[h*IT + i]) * rS[h*IT + i];
            float mk = mask[((size_t)b*NN + i0blk + i)*NN + jt*JT + j];
            wgt[(h*IT + i)*(JT+1) + j] = e * mk;
        }
        __syncthreads();
#pragma unroll 4
        for (int jj = 0; jj < JT; ++jj) {
            float wv[4];
#pragma unroll
            for (int r = 0; r < 4; ++r)
                wv[r] = wgt[(ht*IT + i0 + r)*(JT+1) + jj];
            float hv[16];
#pragma unroll
            for (int c4 = 0; c4 < 4; ++c4) {
                float4 v = *(const float4*)&hpT[(ht*JT + jj)*FO + oc + c4*4];
                hv[c4*4+0] = v.x; hv[c4*4+1] = v.y; hv[c4*4+2] = v.z; hv[c4*4+3] = v.w;
            }
#pragma unroll
            for (int r = 0; r < 4; ++r)
#pragma unroll
                for (int c = 0; c < 16; ++c)
                    acc[r][c] = fmaf(wv[r], hv[c], acc[r][c]);
        }
    }
    __syncthreads();
    for (int hh = 0; hh < NH; ++hh) {
        if (ht == hh) {
#pragma unroll
            for (int r = 0; r < 4; ++r)
#pragma unroll
                for (int c = 0; c < 16; ++c) {
                    if (hh == 0) outS[(i0+r)*FO + oc + c] = acc[r][c];
                    else         outS[(i0+r)*FO + oc + c] += acc[r][c];
                }
        }
        __syncthreads();
    }
#pragma unroll
    for (int k = 0; k < 4; ++k) {
        int idx4 = t + k*256;
        int i = idx4 >> 4;
        int c4 = idx4 & 15;
        int g = (b*NN + i0blk + i)*FO + c4*4;
        float4 base = *(const float4*)&gat[g];
        float4 v = *(float4*)&outS[i*FO + c4*4];
        v.x += base.x; v.y += base.y; v.z += base.z; v.w += base.w;
        *(float4*)&gat[g] = v;
    }
}

// ---------------- kernel 4a: convert weights to bf16, transposed (n-major) ----------------
// W1T[1024][64], W2T[512][1024], W3T[48][512] (rows 40..47 zero)
__global__ __launch_bounds__(256) void k_conv(
    const float* __restrict__ W1, const float* __restrict__ W2, const float* __restrict__ W3,
    short* __restrict__ w1t, short* __restrict__ w2t, short* __restrict__ w3t)
{
    int idx = blockIdx.x * 256 + threadIdx.x;
    if (idx < HD1*FO) {                       // 65536
        int n = idx >> 6, k = idx & 63;
        w1t[idx] = (short)f2bf(W1[k*HD1 + n]);
    } else if (idx < HD1*FO + HD2*HD1) {      // +524288
        int i2 = idx - HD1*FO;
        int n = i2 >> 10, k = i2 & 1023;
        w2t[i2] = (short)f2bf(W2[k*HD2 + n]);
    } else if (idx < HD1*FO + HD2*HD1 + 48*HD2) {
        int i3 = idx - (HD1*FO + HD2*HD1);
        int n = i3 >> 9, k = i3 & 511;
        w3t[i3] = (short)(n < ODIM ? f2bf(W3[k*ODIM + n]) : 0);
    }
}

// ---------------- kernel 4b: fused MFMA MLP ----------------
// TM=32 rows/block. All GEMMs computed transposed: mfma(W_frag, X_frag, acc)
// so each lane holds 4 consecutive n at fixed m -> b64 LDS epilogue writes.
// LDS: h1 [32][1024] bf16 (64KB, XOR-swizzled); a0 [32][64] bf16 (4KB).
// h2 [32][512] bf16 aliases h1[0:32KB]; GEMM3 partials (f32 [4][32][48]) at h1+32KB.
__global__ __launch_bounds__(256, 1) void k_mlp2(
    const float* __restrict__ gat,
    const short* __restrict__ w1t, const float* __restrict__ b1,
    const short* __restrict__ w2t, const float* __restrict__ b2,
    const short* __restrict__ w3t, const float* __restrict__ b3,
    float* __restrict__ out)
{
    extern __shared__ char smem[];
    char* h1b = smem;                 // 65536 B
    char* a0b = smem + 65536;         // 4096 B
    int t = threadIdx.x;
    int lane = t & 63, wave = t >> 6;
    int m0 = blockIdx.x * 32;

    // ---- phase 0: relu(gat) -> bf16 -> LDS a0 [32][64], swizzled
    {
        int row = t >> 3, c0 = (t & 7) * 8;
        const float4* g = (const float4*)&gat[(size_t)(m0 + row) * FO + c0];
        float4 v0 = g[0], v1 = g[1];
        uint4 p;
        p.x = pack2(fmaxf(v0.x, 0.f), fmaxf(v0.y, 0.f));
        p.y = pack2(fmaxf(v0.z, 0.f), fmaxf(v0.w, 0.f));
        p.z = pack2(fmaxf(v1.x, 0.f), fmaxf(v1.y, 0.f));
        p.w = pack2(fmaxf(v1.z, 0.f), fmaxf(v1.w, 0.f));
        int addr = (row * 128 + c0 * 2) ^ ((row & 7) << 4);
        *(uint4*)(a0b + addr) = p;
    }
    __syncthreads();

    // ---- phase 1: GEMM1 [32x64]@[64x1024] -> relu -> bf16 h1
    for (int c = 0; c < 4; ++c) {
        int n0 = wave * 256 + c * 64;
        f32x4 acc[2][4];
#pragma unroll
        for (int mt = 0; mt < 2; ++mt)
#pragma unroll
            for (int nt = 0; nt < 4; ++nt) acc[mt][nt] = (f32x4)0.f;
#pragma unroll
        for (int ks = 0; ks < 2; ++ks) {
            int k0 = ks * 32;
            bf16x8 xf[2];
#pragma unroll
            for (int mt = 0; mt < 2; ++mt) {
                int row = mt * 16 + (lane & 15);
                int addr = (row * 128 + k0 * 2 + (lane >> 4) * 16) ^ ((row & 7) << 4);
                xf[mt] = *(bf16x8*)(a0b + addr);
            }
#pragma unroll
            for (int nt = 0; nt < 4; ++nt) {
                int col = n0 + nt * 16 + (lane & 15);
                bf16x8 wf = *(const bf16x8*)(w1t + col * 64 + k0 + (lane >> 4) * 8);
#pragma unroll
                for (int mt = 0; mt < 2; ++mt)
                    acc[mt][nt] = __builtin_amdgcn_mfma_f32_16x16x32_bf16(wf, xf[mt], acc[mt][nt], 0, 0, 0);
            }
        }
#pragma unroll
        for (int mt = 0; mt < 2; ++mt)
#pragma unroll
            for (int nt = 0; nt < 4; ++nt) {
                int m = mt * 16 + (lane & 15);
                int nb = n0 + nt * 16 + (lane >> 4) * 4;
                float4 bb = *(const float4*)&b1[nb];
                float v0 = fmaxf(acc[mt][nt][0] + bb.x, 0.f);
                float v1 = fmaxf(acc[mt][nt][1] + bb.y, 0.f);
                float v2 = fmaxf(acc[mt][nt][2] + bb.z, 0.f);
                float v3 = fmaxf(acc[mt][nt][3] + bb.w, 0.f);
                uint2 pw; pw.x = pack2(v0, v1); pw.y = pack2(v2, v3);
                int addr = (m * 2048 + nb * 2) ^ ((m & 7) << 4);
                *(uint2*)(h1b + addr) = pw;
            }
    }
    __syncthreads();

    // ---- phase 2: GEMM2 [32x1024]@[1024x512], W2T streamed from L2
    f32x4 acc2[2][8];
#pragma unroll
    for (int mt = 0; mt < 2; ++mt)
#pragma unroll
        for (int nt = 0; nt < 8; ++nt) acc2[mt][nt] = (f32x4)0.f;
#pragma unroll 4
    for (int ks = 0; ks < 32; ++ks) {
        int k0 = ks * 32;
        bf16x8 xf[2];
#pragma unroll
        for (int mt = 0; mt < 2; ++mt) {
            int m = mt * 16 + (lane & 15);
            int addr = (m * 2048 + k0 * 2 + (lane >> 4) * 16) ^ ((m & 7) << 4);
            xf[mt] = *(bf16x8*)(h1b + addr);
        }
#pragma unroll
        for (int nt = 0; nt < 8; ++nt) {
            int col = wave * 128 + nt * 16 + (lane & 15);
            bf16x8 wf = *(const bf16x8*)(w2t + col * 1024 + k0 + (lane >> 4) * 8);
#pragma unroll
            for (int mt = 0; mt < 2; ++mt)
                acc2[mt][nt] = __builtin_amdgcn_mfma_f32_16x16x32_bf16(wf, xf[mt], acc2[mt][nt], 0, 0, 0);
        }
    }
    __syncthreads();   // all waves done reading h1
    // h2 = relu(acc2 + b2) -> bf16 into h1[0:32KB]
#pragma unroll
    for (int mt = 0; mt < 2; ++mt)
#pragma unroll
        for (int nt = 0; nt < 8; ++nt) {
            int m = mt * 16 + (lane & 15);
            int nb = wave * 128 + nt * 16 + (lane >> 4) * 4;
            float4 bb = *(const float4*)&b2[nb];
            float v0 = fmaxf(acc2[mt][nt][0] + bb.x, 0.f);
            float v1 = fmaxf(acc2[mt][nt][1] + bb.y, 0.f);
            float v2 = fmaxf(acc2[mt][nt][2] + bb.z, 0.f);
            float v3 = fmaxf(acc2[mt][nt][3] + bb.w, 0.f);
            uint2 pw; pw.x = pack2(v0, v1); pw.y = pack2(v2, v3);
            int addr = (m * 1024 + nb * 2) ^ ((m & 7) << 4);
            *(uint2*)(h1b + addr) = pw;
        }
    __syncthreads();

    // ---- phase 3: GEMM3 [32x512]@[512x48], K split across 4 waves
    f32x4 acc3[2][3];
#pragma unroll
    for (int mt = 0; mt < 2; ++mt)
#pragma unroll
        for (int nt = 0; nt < 3; ++nt) acc3[mt][nt] = (f32x4)0.f;
#pragma unroll
    for (int ks = 0; ks < 4; ++ks) {
        int k0 = wave * 128 + ks * 32;
        bf16x8 xf[2];
#pragma unroll
        for (int mt = 0; mt < 2; ++mt) {
            int m = mt * 16 + (lane & 15);
            int addr = (m * 1024 + k0 * 2 + (lane >> 4) * 16) ^ ((m & 7) << 4);
            xf[mt] = *(bf16x8*)(h1b + addr);
        }
#pragma unroll
        for (int nt = 0; nt < 3; ++nt) {
            int col = nt * 16 + (lane & 15);
            bf16x8 wf = *(const bf16x8*)(w3t + col * 512 + k0 + (lane >> 4) * 8);
#pragma unroll
            for (int mt = 0; mt < 2; ++mt)
                acc3[mt][nt] = __builtin_amdgcn_mfma_f32_16x16x32_bf16(wf, xf[mt], acc3[mt][nt], 0, 0, 0);
        }
    }
    float* part = (float*)(h1b + 32768);   // [4][32][48] f32
#pragma unroll
    for (int mt = 0; mt < 2; ++mt)
#pragma unroll
        for (int nt = 0; nt < 3; ++nt) {
            int m = mt * 16 + (lane & 15);
            int nb = nt * 16 + (lane >> 4) * 4;
            float4 v = {acc3[mt][nt][0], acc3[mt][nt][1], acc3[mt][nt][2], acc3[mt][nt][3]};
            *(float4*)&part[(wave * 32 + m) * 48 + nb] = v;
        }
    __syncthreads();
    // reduce over waves + bias + sigmoid + clip
#pragma unroll
    for (int i = 0; i < 5; ++i) {
        int o = t + i * 256;               // 1280 = 32*40
        int m = o / ODIM, n = o - m * ODIM;
        float s = b3[n];
#pragma unroll
        for (int wv = 0; wv < 4; ++wv) s += part[(wv * 32 + m) * 48 + n];
        s = 1.f / (1.f + __expf(-s));
        s = fminf(fmaxf(s, 0.01f), 0.99f);
        out[(size_t)(m0 + m) * ODIM + n] = s;
    }
}

extern "C" void kernel_launch(void* const* d_in, const int* in_sizes, int n_in,
                              void* d_out, int out_size, void* d_ws, size_t ws_size,
                              hipStream_t stream)
{
    const float* x     = (const float*)d_in[0];
    const float* mask  = (const float*)d_in[1];
    const float* w     = (const float*)d_in[2];
    const float* a_src = (const float*)d_in[3];
    const float* a_dst = (const float*)d_in[4];
    const float* bias  = (const float*)d_in[5];
    const float* W1    = (const float*)d_in[6];
    const float* b1    = (const float*)d_in[7];
    const float* W2    = (const float*)d_in[8];
    const float* b2    = (const float*)d_in[9];
    const float* W3    = (const float*)d_in[10];
    const float* b3    = (const float*)d_in[11];
    float* out = (float*)d_out;

    float* ws   = (float*)d_ws;
    float* hp   = ws;                                   // [B][H][N][64]  (32 MiB)
    float* asrc = hp   + (size_t)BB*NH*NN*FO;
    float* adst = asrc + (size_t)BB*NH*NN;
    float* rm   = adst + (size_t)BB*NH*NN;
    float* rr   = rm   + (size_t)BB*NH*NN;
    float* gat  = rr   + (size_t)BB*NH*NN;              // [B][N][64]  (8 MiB)
    // bf16 weights overlay hp (dead after k_attn; k_conv runs after k_attn)
    short* w1t = (short*)hp;                            // [1024][64]
    short* w2t = w1t + HD1*FO;                          // [512][1024]
    short* w3t = w2t + HD2*HD1;                         // [48][512]

    k_proj <<<BB*NN, 256, 0, stream>>>(x, w, a_src, a_dst, bias, hp, asrc, adst, gat);
    k_stats<<<BB*NH, 256, 0, stream>>>(asrc, adst, rm, rr);
    k_attn <<<dim3(NN/IT, BB), 256, 0, stream>>>(hp, mask, asrc, adst, rm, rr, gat);
    k_conv <<<(HD1*FO + HD2*HD1 + 48*HD2 + 255)/256, 256, 0, stream>>>(W1, W2, W3, w1t, w2t, w3t);
    k_mlp2 <<<BB*NN/32, 256, 69632, stream>>>(gat, w1t, b1, w2t, b2, w3t, b3, out);
}

// Round 4
// 340.001 us; speedup vs baseline: 3.7439x; 1.9789x over previous
//
#include <hip/hip_runtime.h>
#include <math.h>

typedef short bf16x8 __attribute__((ext_vector_type(8)));
typedef float f32x4 __attribute__((ext_vector_type(4)));

#define BB 64
#define NN 512
#define NH 4
#define FI 16
#define FO 64
#define HD1 1024
#define HD2 512
#define ODIM 40

__device__ __forceinline__ unsigned short f2bf(float f) {
    unsigned u = __float_as_uint(f);
    u += 0x7fffu + ((u >> 16) & 1u);        // RNE
    return (unsigned short)(u >> 16);
}
__device__ __forceinline__ unsigned pack2(float a, float b) {
    return (unsigned)f2bf(a) | ((unsigned)f2bf(b) << 16);
}

// ---------------- kernel 0: wa[h][i] = sum_o w[h][i][o] * a_{src,dst}[h][o] ----------------
__global__ void k_wa(const float* __restrict__ w, const float* __restrict__ a_src,
                     const float* __restrict__ a_dst, float* __restrict__ wa)
{
    int t = threadIdx.x;      // 0..63 = h*16+i
    int h = t >> 4;
    float s = 0.f, d = 0.f;
    for (int o = 0; o < FO; ++o) {
        float wv = w[t*FO + o];
        s = fmaf(wv, a_src[h*FO + o], s);
        d = fmaf(wv, a_dst[h*FO + o], d);
    }
    wa[t] = s; wa[64 + t] = d;
}

// ---------------- kernel 1: projection -> hpT bf16 (transposed), asrc/adst, gat=bias+skip ----------------
// block = (n-tile of 64, b); thread = (h = t>>6, o = t&63), loops 64 nodes in registers.
__global__ __launch_bounds__(256) void k_proj2(
    const float* __restrict__ x, const float* __restrict__ w,
    const float* __restrict__ bias, const float* __restrict__ wa,
    short* __restrict__ hpT,           // [B*H][64 o][512 n] bf16
    float* __restrict__ asrc, float* __restrict__ adst,
    float* __restrict__ gat)
{
    __shared__ float xS[64][20];       // padded (rows 80B, 16B-aligned float4 reads)
    __shared__ float gS[NH][64][64];   // 64KB per-head partials
    int b = blockIdx.y;
    int n0 = blockIdx.x * 64;
    int t = threadIdx.x;
    int h = t >> 6, o = t & 63;
    {
        // 64 rows x 16 floats = 256 float4 loads: exactly one per thread
        int n = t >> 2, q = t & 3;
        float4 v = *(const float4*)&x[((size_t)b*NN + n0 + n)*FI + q*4];
        *(float4*)&xS[n][q*4] = v;
    }
    float wreg[16];
#pragma unroll
    for (int i = 0; i < FI; ++i) wreg[i] = w[(h*FI + i)*FO + o];
    __syncthreads();

    size_t hbase = ((size_t)(b*NH + h)*FO + o) * NN + n0;
    for (int nc = 0; nc < 8; ++nc) {
        float acc[8];
#pragma unroll
        for (int k = 0; k < 8; ++k) {
            int n = nc*8 + k;
            float4 a0 = *(const float4*)&xS[n][0];
            float4 a1 = *(const float4*)&xS[n][4];
            float4 a2 = *(const float4*)&xS[n][8];
            float4 a3 = *(const float4*)&xS[n][12];
            float sA = fmaf(a0.x, wreg[0], fmaf(a0.y, wreg[1], fmaf(a0.z, wreg[2], a0.w*wreg[3])));
            float sB = fmaf(a1.x, wreg[4], fmaf(a1.y, wreg[5], fmaf(a1.z, wreg[6], a1.w*wreg[7])));
            float sC = fmaf(a2.x, wreg[8], fmaf(a2.y, wreg[9], fmaf(a2.z, wreg[10], a2.w*wreg[11])));
            float sD = fmaf(a3.x, wreg[12], fmaf(a3.y, wreg[13], fmaf(a3.z, wreg[14], a3.w*wreg[15])));
            float s = (sA + sB) + (sC + sD);
            acc[k] = s;
            gS[h][n][o] = s;
        }
        uint4 p;
        p.x = pack2(acc[0], acc[1]); p.y = pack2(acc[2], acc[3]);
        p.z = pack2(acc[4], acc[5]); p.w = pack2(acc[6], acc[7]);
        *(uint4*)&hpT[hbase + nc*8] = p;
    }
    // attn scalars: lane computes node n = o via reassociated dot with wa
    {
        int n = o;
        float vs = 0.f, vd = 0.f;
#pragma unroll
        for (int i = 0; i < FI; ++i) {
            float xv = xS[n][i];
            vs = fmaf(xv, wa[h*FI + i], vs);
            vd = fmaf(xv, wa[64 + h*FI + i], vd);
        }
        asrc[(size_t)(b*NH + h)*NN + n0 + n] = vs;
        adst[(size_t)(b*NH + h)*NN + n0 + n] = vd;
    }
    __syncthreads();
#pragma unroll
    for (int r = 0; r < 16; ++r) {
        int idx = t + r*256;
        int n = idx >> 6, oo = idx & 63;
        float g = bias[oo] + ((gS[0][n][oo] + gS[1][n][oo]) + (gS[2][n][oo] + gS[3][n][oo]));
        gat[((size_t)b*NN + n0 + n)*FO + oo] = g;
    }
}

// ---------------- kernel 2: per-row softmax stats (max, 1/sumexp) ----------------
__global__ __launch_bounds__(256) void k_stats(
    const float* __restrict__ asrc, const float* __restrict__ adst,
    float* __restrict__ rm, float* __restrict__ rr)
{
    int bh = blockIdx.x;              // b*NH + h
    __shared__ float d[NN];
    int t = threadIdx.x;
    for (int j = t; j < NN; j += 256) d[j] = adst[bh * NN + j];
    __syncthreads();
    for (int i = t; i < NN; i += 256) {
        float s = asrc[bh * NN + i];
        float m = -INFINITY;
        for (int j = 0; j < NN; ++j) {
            float v = s * d[j];
            v = fmaxf(v, 0.2f * v);
            m = fmaxf(m, v);
        }
        float sum = 0.f;
        for (int j = 0; j < NN; ++j) {
            float v = s * d[j];
            v = fmaxf(v, 0.2f * v);
            sum += __expf(v - m);
        }
        rm[bh * NN + i] = m;
        rr[bh * NN + i] = 1.0f / sum;   // mask applied AFTER softmax
    }
}

// ---------------- kernel 3: MFMA attention: P generated in-register, K=(h,j)=2048 ----------------
__global__ __launch_bounds__(256) void k_attn2(
    const short* __restrict__ hpT, const float* __restrict__ mask,
    const float* __restrict__ asrc, const float* __restrict__ rm, const float* __restrict__ rr,
    const float* __restrict__ adst,
    float* __restrict__ gat)
{
    __shared__ float dS[NH*NN];       // 8KB
    int b = blockIdx.y;
    int i0blk = blockIdx.x * 64;
    int t = threadIdx.x;
#pragma unroll
    for (int r = 0; r < 8; ++r) {
        int idx = t + r*256;
        dS[idx] = adst[(size_t)b*(NH*NN) + idx];
    }
    int wv = t >> 6, lane = t & 63;
    int li = lane & 15, kq = lane >> 4;
    int i = i0blk + wv*16 + li;
    float s[NH], m[NH], rcp[NH];
#pragma unroll
    for (int h = 0; h < NH; ++h) {
        size_t ix = (size_t)(b*NH + h)*NN + i;
        s[h] = asrc[ix]; m[h] = rm[ix]; rcp[h] = rr[ix];
    }
    __syncthreads();
    f32x4 acc[4];
#pragma unroll
    for (int ot = 0; ot < 4; ++ot) acc[ot] = (f32x4)0.f;

    const float* mrow = &mask[((size_t)b*NN + i)*NN];
    for (int jt = 0; jt < 16; ++jt) {
        int jj = jt*32 + kq*8;
        float4 mk0 = *(const float4*)&mrow[jj];
        float4 mk1 = *(const float4*)&mrow[jj+4];
        float mk[8] = {mk0.x, mk0.y, mk0.z, mk0.w, mk1.x, mk1.y, mk1.z, mk1.w};
#pragma unroll
        for (int h = 0; h < NH; ++h) {
            float4 d0 = *(const float4*)&dS[h*NN + jj];
            float4 d1 = *(const float4*)&dS[h*NN + jj+4];
            float dv[8] = {d0.x,d0.y,d0.z,d0.w,d1.x,d1.y,d1.z,d1.w};
            union { bf16x8 v; unsigned u[4]; } pf;
#pragma unroll
            for (int q = 0; q < 4; ++q) {
                float v0 = s[h]*dv[2*q];   v0 = fmaxf(v0, 0.2f*v0);
                float v1 = s[h]*dv[2*q+1]; v1 = fmaxf(v1, 0.2f*v1);
                float e0 = __expf(v0 - m[h]) * rcp[h] * mk[2*q];
                float e1 = __expf(v1 - m[h]) * rcp[h] * mk[2*q+1];
                pf.u[q] = pack2(e0, e1);
            }
            const short* vbase = &hpT[(size_t)(b*NH + h)*FO*NN + jj];
#pragma unroll
            for (int ot = 0; ot < 4; ++ot) {
                bf16x8 vf = *(const bf16x8*)&vbase[(size_t)(ot*16 + li)*NN];
                acc[ot] = __builtin_amdgcn_mfma_f32_16x16x32_bf16(pf.v, vf, acc[ot], 0, 0, 0);
            }
        }
    }
    // D layout: row (i-within-16) = kq*4+g, col (o-within-16) = li
#pragma unroll
    for (int ot = 0; ot < 4; ++ot) {
#pragma unroll
        for (int g = 0; g < 4; ++g) {
            int ii = i0blk + wv*16 + kq*4 + g;
            int oo = ot*16 + li;
            size_t ix = ((size_t)b*NN + ii)*FO + oo;
            gat[ix] += acc[ot][g];
        }
    }
}

// ---------------- kernel 4a: convert MLP weights to bf16, transposed (n-major) ----------------
__global__ __launch_bounds__(256) void k_conv(
    const float* __restrict__ W1, const float* __restrict__ W2, const float* __restrict__ W3,
    short* __restrict__ w1t, short* __restrict__ w2t, short* __restrict__ w3t)
{
    int idx = blockIdx.x * 256 + threadIdx.x;
    if (idx < HD1*FO) {
        int n = idx >> 6, k = idx & 63;
        w1t[idx] = (short)f2bf(W1[k*HD1 + n]);
    } else if (idx < HD1*FO + HD2*HD1) {
        int i2 = idx - HD1*FO;
        int n = i2 >> 10, k = i2 & 1023;
        w2t[i2] = (short)f2bf(W2[k*HD2 + n]);
    } else if (idx < HD1*FO + HD2*HD1 + 48*HD2) {
        int i3 = idx - (HD1*FO + HD2*HD1);
        int n = i3 >> 9, k = i3 & 511;
        w3t[i3] = (short)(n < ODIM ? f2bf(W3[k*ODIM + n]) : 0);
    }
}

// ---------------- kernel 4b: fused MFMA MLP ----------------
__global__ __launch_bounds__(256, 1) void k_mlp2(
    const float* __restrict__ gat,
    const short* __restrict__ w1t, const float* __restrict__ b1,
    const short* __restrict__ w2t, const float* __restrict__ b2,
    const short* __restrict__ w3t, const float* __restrict__ b3,
    float* __restrict__ out)
{
    extern __shared__ char smem[];
    char* h1b = smem;                 // 65536 B
    char* a0b = smem + 65536;         // 4096 B
    int t = threadIdx.x;
    int lane = t & 63, wave = t >> 6;
    int m0 = blockIdx.x * 32;

    {
        int row = t >> 3, c0 = (t & 7) * 8;
        const float4* g = (const float4*)&gat[(size_t)(m0 + row) * FO + c0];
        float4 v0 = g[0], v1 = g[1];
        uint4 p;
        p.x = pack2(fmaxf(v0.x, 0.f), fmaxf(v0.y, 0.f));
        p.y = pack2(fmaxf(v0.z, 0.f), fmaxf(v0.w, 0.f));
        p.z = pack2(fmaxf(v1.x, 0.f), fmaxf(v1.y, 0.f));
        p.w = pack2(fmaxf(v1.z, 0.f), fmaxf(v1.w, 0.f));
        int addr = (row * 128 + c0 * 2) ^ ((row & 7) << 4);
        *(uint4*)(a0b + addr) = p;
    }
    __syncthreads();

    for (int c = 0; c < 4; ++c) {
        int n0 = wave * 256 + c * 64;
        f32x4 acc[2][4];
#pragma unroll
        for (int mt = 0; mt < 2; ++mt)
#pragma unroll
            for (int nt = 0; nt < 4; ++nt) acc[mt][nt] = (f32x4)0.f;
#pragma unroll
        for (int ks = 0; ks < 2; ++ks) {
            int k0 = ks * 32;
            bf16x8 xf[2];
#pragma unroll
            for (int mt = 0; mt < 2; ++mt) {
                int row = mt * 16 + (lane & 15);
                int addr = (row * 128 + k0 * 2 + (lane >> 4) * 16) ^ ((row & 7) << 4);
                xf[mt] = *(bf16x8*)(a0b + addr);
            }
#pragma unroll
            for (int nt = 0; nt < 4; ++nt) {
                int col = n0 + nt * 16 + (lane & 15);
                bf16x8 wf = *(const bf16x8*)(w1t + col * 64 + k0 + (lane >> 4) * 8);
#pragma unroll
                for (int mt = 0; mt < 2; ++mt)
                    acc[mt][nt] = __builtin_amdgcn_mfma_f32_16x16x32_bf16(wf, xf[mt], acc[mt][nt], 0, 0, 0);
            }
        }
#pragma unroll
        for (int mt = 0; mt < 2; ++mt)
#pragma unroll
            for (int nt = 0; nt < 4; ++nt) {
                int m = mt * 16 + (lane & 15);
                int nb = n0 + nt * 16 + (lane >> 4) * 4;
                float4 bb = *(const float4*)&b1[nb];
                float v0 = fmaxf(acc[mt][nt][0] + bb.x, 0.f);
                float v1 = fmaxf(acc[mt][nt][1] + bb.y, 0.f);
                float v2 = fmaxf(acc[mt][nt][2] + bb.z, 0.f);
                float v3 = fmaxf(acc[mt][nt][3] + bb.w, 0.f);
                uint2 pw; pw.x = pack2(v0, v1); pw.y = pack2(v2, v3);
                int addr = (m * 2048 + nb * 2) ^ ((m & 7) << 4);
                *(uint2*)(h1b + addr) = pw;
            }
    }
    __syncthreads();

    f32x4 acc2[2][8];
#pragma unroll
    for (int mt = 0; mt < 2; ++mt)
#pragma unroll
        for (int nt = 0; nt < 8; ++nt) acc2[mt][nt] = (f32x4)0.f;
#pragma unroll 4
    for (int ks = 0; ks < 32; ++ks) {
        int k0 = ks * 32;
        bf16x8 xf[2];
#pragma unroll
        for (int mt = 0; mt < 2; ++mt) {
            int m = mt * 16 + (lane & 15);
            int addr = (m * 2048 + k0 * 2 + (lane >> 4) * 16) ^ ((m & 7) << 4);
            xf[mt] = *(bf16x8*)(h1b + addr);
        }
#pragma unroll
        for (int nt = 0; nt < 8; ++nt) {
            int col = wave * 128 + nt * 16 + (lane & 15);
            bf16x8 wf = *(const bf16x8*)(w2t + col * 1024 + k0 + (lane >> 4) * 8);
#pragma unroll
            for (int mt = 0; mt < 2; ++mt)
                acc2[mt][nt] = __builtin_amdgcn_mfma_f32_16x16x32_bf16(wf, xf[mt], acc2[mt][nt], 0, 0, 0);
        }
    }
    __syncthreads();
#pragma unroll
    for (int mt = 0; mt < 2; ++mt)
#pragma unroll
        for (int nt = 0; nt < 8; ++nt) {
            int m = mt * 16 + (lane & 15);
            int nb = wave * 128 + nt * 16 + (lane >> 4) * 4;
            float4 bb = *(const float4*)&b2[nb];
            float v0 = fmaxf(acc2[mt][nt][0] + bb.x, 0.f);
            float v1 = fmaxf(acc2[mt][nt][1] + bb.y, 0.f);
            float v2 = fmaxf(acc2[mt][nt][2] + bb.z, 0.f);
            float v3 = fmaxf(acc2[mt][nt][3] + bb.w, 0.f);
            uint2 pw; pw.x = pack2(v0, v1); pw.y = pack2(v2, v3);
            int addr = (m * 1024 + nb * 2) ^ ((m & 7) << 4);
            *(uint2*)(h1b + addr) = pw;
        }
    __syncthreads();

    f32x4 acc3[2][3];
#pragma unroll
    for (int mt = 0; mt < 2; ++mt)
#pragma unroll
        for (int nt = 0; nt < 3; ++nt) acc3[mt][nt] = (f32x4)0.f;
#pragma unroll
    for (int ks = 0; ks < 4; ++ks) {
        int k0 = wave * 128 + ks * 32;
        bf16x8 xf[2];
#pragma unroll
        for (int mt = 0; mt < 2; ++mt) {
            int m = mt * 16 + (lane & 15);
            int addr = (m * 1024 + k0 * 2 + (lane >> 4) * 16) ^ ((m & 7) << 4);
            xf[mt] = *(bf16x8*)(h1b + addr);
        }
#pragma unroll
        for (int nt = 0; nt < 3; ++nt) {
            int col = nt * 16 + (lane & 15);
            bf16x8 wf = *(const bf16x8*)(w3t + col * 512 + k0 + (lane >> 4) * 8);
#pragma unroll
            for (int mt = 0; mt < 2; ++mt)
                acc3[mt][nt] = __builtin_amdgcn_mfma_f32_16x16x32_bf16(wf, xf[mt], acc3[mt][nt], 0, 0, 0);
        }
    }
    float* part = (float*)(h1b + 32768);   // [4][32][48] f32
#pragma unroll
    for (int mt = 0; mt < 2; ++mt)
#pragma unroll
        for (int nt = 0; nt < 3; ++nt) {
            int m = mt * 16 + (lane & 15);
            int nb = nt * 16 + (lane >> 4) * 4;
            float4 v = {acc3[mt][nt][0], acc3[mt][nt][1], acc3[mt][nt][2], acc3[mt][nt][3]};
            *(float4*)&part[(wave * 32 + m) * 48 + nb] = v;
        }
    __syncthreads();
#pragma unroll
    for (int i = 0; i < 5; ++i) {
        int o = t + i * 256;               // 1280 = 32*40
        int m = o / ODIM, n = o - m * ODIM;
        float s = b3[n];
#pragma unroll
        for (int wv = 0; wv < 4; ++wv) s += part[(wv * 32 + m) * 48 + n];
        s = 1.f / (1.f + __expf(-s));
        s = fminf(fmaxf(s, 0.01f), 0.99f);
        out[(size_t)(m0 + m) * ODIM + n] = s;
    }
}

extern "C" void kernel_launch(void* const* d_in, const int* in_sizes, int n_in,
                              void* d_out, int out_size, void* d_ws, size_t ws_size,
                              hipStream_t stream)
{
    const float* x     = (const float*)d_in[0];
    const float* mask  = (const float*)d_in[1];
    const float* w     = (const float*)d_in[2];
    const float* a_src = (const float*)d_in[3];
    const float* a_dst = (const float*)d_in[4];
    const float* bias  = (const float*)d_in[5];
    const float* W1    = (const float*)d_in[6];
    const float* b1    = (const float*)d_in[7];
    const float* W2    = (const float*)d_in[8];
    const float* b2    = (const float*)d_in[9];
    const float* W3    = (const float*)d_in[10];
    const float* b3    = (const float*)d_in[11];
    float* out = (float*)d_out;

    char* p = (char*)d_ws;
    short* hpT = (short*)p;  p += (size_t)BB*NH*FO*NN*2;   // 16.78 MB
    float* asrc = (float*)p; p += (size_t)BB*NH*NN*4;
    float* adst = (float*)p; p += (size_t)BB*NH*NN*4;
    float* rm   = (float*)p; p += (size_t)BB*NH*NN*4;
    float* rr   = (float*)p; p += (size_t)BB*NH*NN*4;
    float* gat  = (float*)p; p += (size_t)BB*NN*FO*4;      // 8.39 MB
    short* w1t  = (short*)p; p += (size_t)HD1*FO*2;
    short* w2t  = (short*)p; p += (size_t)HD2*HD1*2;
    short* w3t  = (short*)p; p += (size_t)48*HD2*2;
    float* wa   = (float*)p; p += 128*4;                   // total ~28.6 MB

    k_wa   <<<1, 64, 0, stream>>>(w, a_src, a_dst, wa);
    k_conv <<<(HD1*FO + HD2*HD1 + 48*HD2)/256, 256, 0, stream>>>(W1, W2, W3, w1t, w2t, w3t);
    k_proj2<<<dim3(NN/64, BB), 256, 0, stream>>>(x, w, bias, wa, hpT, asrc, adst, gat);
    k_stats<<<BB*NH, 256, 0, stream>>>(asrc, adst, rm, rr);
    k_attn2<<<dim3(NN/64, BB), 256, 0, stream>>>(hpT, mask, asrc, rm, rr, adst, gat);
    k_mlp2 <<<BB*NN/32, 256, 69632, stream>>>(gat, w1t, b1, w2t, b2, w3t, b3, out);
}

// Round 5
// 273.323 us; speedup vs baseline: 4.6572x; 1.2440x over previous
//
#include <hip/hip_runtime.h>
#include <math.h>

typedef short bf16x8 __attribute__((ext_vector_type(8)));
typedef float f32x4 __attribute__((ext_vector_type(4)));

#define BB 64
#define NN 512
#define NH 4
#define FI 16
#define FO 64
#define HD1 1024
#define HD2 512
#define ODIM 40

__device__ __forceinline__ unsigned short f2bf(float f) {
    unsigned u = __float_as_uint(f);
    u += 0x7fffu + ((u >> 16) & 1u);        // RNE
    return (unsigned short)(u >> 16);
}
__device__ __forceinline__ unsigned pack2(float a, float b) {
    return (unsigned)f2bf(a) | ((unsigned)f2bf(b) << 16);
}

// ---------------- kernel 0: wa[h][i] = sum_o w[h][i][o] * a_{src,dst}[h][o] ----------------
__global__ void k_wa(const float* __restrict__ w, const float* __restrict__ a_src,
                     const float* __restrict__ a_dst, float* __restrict__ wa)
{
    int t = threadIdx.x;      // 0..63 = h*16+i
    int h = t >> 4;
    float s = 0.f, d = 0.f;
    for (int o = 0; o < FO; ++o) {
        float wv = w[t*FO + o];
        s = fmaf(wv, a_src[h*FO + o], s);
        d = fmaf(wv, a_dst[h*FO + o], d);
    }
    wa[t] = s; wa[64 + t] = d;
}

// ---------------- kernel 1: projection -> hpT bf16 (transposed), asrc/adst, gat=bias+skip ----------------
__global__ __launch_bounds__(256) void k_proj2(
    const float* __restrict__ x, const float* __restrict__ w,
    const float* __restrict__ bias, const float* __restrict__ wa,
    short* __restrict__ hpT,           // [B*H][64 o][512 n] bf16
    float* __restrict__ asrc, float* __restrict__ adst,
    float* __restrict__ gat)
{
    __shared__ float xS[64][20];       // padded (rows 80B, 16B-aligned float4 reads)
    __shared__ float gS[NH][64][64];   // 64KB per-head partials
    int b = blockIdx.y;
    int n0 = blockIdx.x * 64;
    int t = threadIdx.x;
    int h = t >> 6, o = t & 63;
    {
        // 64 rows x 16 floats = 256 float4 loads: exactly one per thread
        int n = t >> 2, q = t & 3;
        float4 v = *(const float4*)&x[((size_t)b*NN + n0 + n)*FI + q*4];
        *(float4*)&xS[n][q*4] = v;
    }
    float wreg[16];
#pragma unroll
    for (int i = 0; i < FI; ++i) wreg[i] = w[(h*FI + i)*FO + o];
    __syncthreads();

    size_t hbase = ((size_t)(b*NH + h)*FO + o) * NN + n0;
    for (int nc = 0; nc < 8; ++nc) {
        float acc[8];
#pragma unroll
        for (int k = 0; k < 8; ++k) {
            int n = nc*8 + k;
            float4 a0 = *(const float4*)&xS[n][0];
            float4 a1 = *(const float4*)&xS[n][4];
            float4 a2 = *(const float4*)&xS[n][8];
            float4 a3 = *(const float4*)&xS[n][12];
            float sA = fmaf(a0.x, wreg[0], fmaf(a0.y, wreg[1], fmaf(a0.z, wreg[2], a0.w*wreg[3])));
            float sB = fmaf(a1.x, wreg[4], fmaf(a1.y, wreg[5], fmaf(a1.z, wreg[6], a1.w*wreg[7])));
            float sC = fmaf(a2.x, wreg[8], fmaf(a2.y, wreg[9], fmaf(a2.z, wreg[10], a2.w*wreg[11])));
            float sD = fmaf(a3.x, wreg[12], fmaf(a3.y, wreg[13], fmaf(a3.z, wreg[14], a3.w*wreg[15])));
            float s = (sA + sB) + (sC + sD);
            acc[k] = s;
            gS[h][n][o] = s;
        }
        uint4 p;
        p.x = pack2(acc[0], acc[1]); p.y = pack2(acc[2], acc[3]);
        p.z = pack2(acc[4], acc[5]); p.w = pack2(acc[6], acc[7]);
        *(uint4*)&hpT[hbase + nc*8] = p;
    }
    {
        int n = o;
        float vs = 0.f, vd = 0.f;
#pragma unroll
        for (int i = 0; i < FI; ++i) {
            float xv = xS[n][i];
            vs = fmaf(xv, wa[h*FI + i], vs);
            vd = fmaf(xv, wa[64 + h*FI + i], vd);
        }
        asrc[(size_t)(b*NH + h)*NN + n0 + n] = vs;
        adst[(size_t)(b*NH + h)*NN + n0 + n] = vd;
    }
    __syncthreads();
#pragma unroll
    for (int r = 0; r < 16; ++r) {
        int idx = t + r*256;
        int n = idx >> 6, oo = idx & 63;
        float g = bias[oo] + ((gS[0][n][oo] + gS[1][n][oo]) + (gS[2][n][oo] + gS[3][n][oo]));
        gat[((size_t)b*NN + n0 + n)*FO + oo] = g;
    }
}

// ---------------- kernel 2: per-row softmax stats (max, 1/sumexp) ----------------
__global__ __launch_bounds__(256) void k_stats(
    const float* __restrict__ asrc, const float* __restrict__ adst,
    float* __restrict__ rm, float* __restrict__ rr)
{
    int bh = blockIdx.x;              // b*NH + h
    __shared__ float d[NN];
    int t = threadIdx.x;
    for (int j = t; j < NN; j += 256) d[j] = adst[bh * NN + j];
    __syncthreads();
    for (int i = t; i < NN; i += 256) {
        float s = asrc[bh * NN + i];
        float m = -INFINITY;
        for (int j = 0; j < NN; ++j) {
            float v = s * d[j];
            v = fmaxf(v, 0.2f * v);
            m = fmaxf(m, v);
        }
        float sum = 0.f;
        for (int j = 0; j < NN; ++j) {
            float v = s * d[j];
            v = fmaxf(v, 0.2f * v);
            sum += __expf(v - m);
        }
        rm[bh * NN + i] = m;
        rr[bh * NN + i] = 1.0f / sum;   // mask applied AFTER softmax
    }
}

// ---------------- kernel 3: MFMA attention: P generated in-register, K=(h,j)=2048 ----------------
__global__ __launch_bounds__(256) void k_attn2(
    const short* __restrict__ hpT, const float* __restrict__ mask,
    const float* __restrict__ asrc, const float* __restrict__ rm, const float* __restrict__ rr,
    const float* __restrict__ adst,
    float* __restrict__ gat)
{
    __shared__ float dS[NH*NN];       // 8KB
    int b = blockIdx.y;
    int i0blk = blockIdx.x * 64;
    int t = threadIdx.x;
#pragma unroll
    for (int r = 0; r < 8; ++r) {
        int idx = t + r*256;
        dS[idx] = adst[(size_t)b*(NH*NN) + idx];
    }
    int wv = t >> 6, lane = t & 63;
    int li = lane & 15, kq = lane >> 4;
    int i = i0blk + wv*16 + li;
    float s[NH], m[NH], rcp[NH];
#pragma unroll
    for (int h = 0; h < NH; ++h) {
        size_t ix = (size_t)(b*NH + h)*NN + i;
        s[h] = asrc[ix]; m[h] = rm[ix]; rcp[h] = rr[ix];
    }
    __syncthreads();
    f32x4 acc[4];
#pragma unroll
    for (int ot = 0; ot < 4; ++ot) acc[ot] = (f32x4)0.f;

    const float* mrow = &mask[((size_t)b*NN + i)*NN];
    for (int jt = 0; jt < 16; ++jt) {
        int jj = jt*32 + kq*8;
        float4 mk0 = *(const float4*)&mrow[jj];
        float4 mk1 = *(const float4*)&mrow[jj+4];
        float mk[8] = {mk0.x, mk0.y, mk0.z, mk0.w, mk1.x, mk1.y, mk1.z, mk1.w};
#pragma unroll
        for (int h = 0; h < NH; ++h) {
            float4 d0 = *(const float4*)&dS[h*NN + jj];
            float4 d1 = *(const float4*)&dS[h*NN + jj+4];
            float dv[8] = {d0.x,d0.y,d0.z,d0.w,d1.x,d1.y,d1.z,d1.w};
            union { bf16x8 v; unsigned u[4]; } pf;
#pragma unroll
            for (int q = 0; q < 4; ++q) {
                float v0 = s[h]*dv[2*q];   v0 = fmaxf(v0, 0.2f*v0);
                float v1 = s[h]*dv[2*q+1]; v1 = fmaxf(v1, 0.2f*v1);
                float e0 = __expf(v0 - m[h]) * rcp[h] * mk[2*q];
                float e1 = __expf(v1 - m[h]) * rcp[h] * mk[2*q+1];
                pf.u[q] = pack2(e0, e1);
            }
            const short* vbase = &hpT[(size_t)(b*NH + h)*FO*NN + jj];
#pragma unroll
            for (int ot = 0; ot < 4; ++ot) {
                bf16x8 vf = *(const bf16x8*)&vbase[(size_t)(ot*16 + li)*NN];
                acc[ot] = __builtin_amdgcn_mfma_f32_16x16x32_bf16(pf.v, vf, acc[ot], 0, 0, 0);
            }
        }
    }
#pragma unroll
    for (int ot = 0; ot < 4; ++ot) {
#pragma unroll
        for (int g = 0; g < 4; ++g) {
            int ii = i0blk + wv*16 + kq*4 + g;
            int oo = ot*16 + li;
            size_t ix = ((size_t)b*NN + ii)*FO + oo;
            gat[ix] += acc[ot][g];
        }
    }
}

// ---------------- kernel 4a: convert MLP weights to bf16, transposed (n-major) ----------------
__global__ __launch_bounds__(256) void k_conv(
    const float* __restrict__ W1, const float* __restrict__ W2, const float* __restrict__ W3,
    short* __restrict__ w1t, short* __restrict__ w2t, short* __restrict__ w3t)
{
    int idx = blockIdx.x * 256 + threadIdx.x;
    if (idx < HD1*FO) {
        int n = idx >> 6, k = idx & 63;
        w1t[idx] = (short)f2bf(W1[k*HD1 + n]);
    } else if (idx < HD1*FO + HD2*HD1) {
        int i2 = idx - HD1*FO;
        int n = i2 >> 10, k = i2 & 1023;
        w2t[i2] = (short)f2bf(W2[k*HD2 + n]);
    } else if (idx < HD1*FO + HD2*HD1 + 48*HD2) {
        int i3 = idx - (HD1*FO + HD2*HD1);
        int n = i3 >> 9, k = i3 & 511;
        w3t[i3] = (short)(n < ODIM ? f2bf(W3[k*ODIM + n]) : 0);
    }
}

// ---------------- kernel 4b: fused MFMA MLP, M=64/block, 512 thr, 2-deep W2 prefetch ----------------
// LDS: h1 [64][1024] bf16 swizzled (128KB) + a0 [64][64] bf16 (8KB) = 136KB.
// h2 [64][512] bf16 aliases h1[0:64KB]; GEMM3 partials f32 [4][64][48] at h1+64KB (48KB).
__global__ __launch_bounds__(512, 2) void k_mlp2(
    const float* __restrict__ gat,
    const short* __restrict__ w1t, const float* __restrict__ b1,
    const short* __restrict__ w2t, const float* __restrict__ b2,
    const short* __restrict__ w3t, const float* __restrict__ b3,
    float* __restrict__ out)
{
    extern __shared__ char smem[];
    char* h1b = smem;                 // 131072 B
    char* a0b = smem + 131072;        // 8192 B
    int t = threadIdx.x;
    int lane = t & 63, wave = t >> 6;
    int li = lane & 15, kq = lane >> 4;
    int m0 = blockIdx.x * 64;

    // ---- phase 0: relu(gat) -> bf16 -> a0 [64][64], swizzled
    {
        int row = t >> 3, c0 = (t & 7) * 8;
        const float4* g = (const float4*)&gat[(size_t)(m0 + row) * FO + c0];
        float4 v0 = g[0], v1 = g[1];
        uint4 p;
        p.x = pack2(fmaxf(v0.x, 0.f), fmaxf(v0.y, 0.f));
        p.y = pack2(fmaxf(v0.z, 0.f), fmaxf(v0.w, 0.f));
        p.z = pack2(fmaxf(v1.x, 0.f), fmaxf(v1.y, 0.f));
        p.w = pack2(fmaxf(v1.z, 0.f), fmaxf(v1.w, 0.f));
        int addr = (row * 128 + c0 * 2) ^ ((row & 7) << 4);
        *(uint4*)(a0b + addr) = p;
    }
    __syncthreads();

    // ---- phase 1: GEMM1 [64x64]@[64x1024] -> relu -> bf16 h1; wave owns 128 cols
    for (int c = 0; c < 2; ++c) {
        int n0 = wave * 128 + c * 64;
        f32x4 acc[4][4];
#pragma unroll
        for (int mt = 0; mt < 4; ++mt)
#pragma unroll
            for (int nt = 0; nt < 4; ++nt) acc[mt][nt] = (f32x4)0.f;
#pragma unroll
        for (int ks = 0; ks < 2; ++ks) {
            int k0 = ks * 32;
            bf16x8 xf[4];
#pragma unroll
            for (int mt = 0; mt < 4; ++mt) {
                int row = mt * 16 + li;
                int addr = (row * 128 + k0 * 2 + kq * 16) ^ ((row & 7) << 4);
                xf[mt] = *(bf16x8*)(a0b + addr);
            }
#pragma unroll
            for (int nt = 0; nt < 4; ++nt) {
                int col = n0 + nt * 16 + li;
                bf16x8 wf = *(const bf16x8*)(w1t + col * 64 + k0 + kq * 8);
#pragma unroll
                for (int mt = 0; mt < 4; ++mt)
                    acc[mt][nt] = __builtin_amdgcn_mfma_f32_16x16x32_bf16(wf, xf[mt], acc[mt][nt], 0, 0, 0);
            }
        }
#pragma unroll
        for (int mt = 0; mt < 4; ++mt)
#pragma unroll
            for (int nt = 0; nt < 4; ++nt) {
                int m = mt * 16 + li;
                int nb = n0 + nt * 16 + kq * 4;
                float4 bb = *(const float4*)&b1[nb];
                float v0 = fmaxf(acc[mt][nt][0] + bb.x, 0.f);
                float v1 = fmaxf(acc[mt][nt][1] + bb.y, 0.f);
                float v2 = fmaxf(acc[mt][nt][2] + bb.z, 0.f);
                float v3 = fmaxf(acc[mt][nt][3] + bb.w, 0.f);
                uint2 pw; pw.x = pack2(v0, v1); pw.y = pack2(v2, v3);
                int addr = (m * 2048 + nb * 2) ^ ((m & 7) << 4);
                *(uint2*)(h1b + addr) = pw;
            }
    }
    __syncthreads();

    // ---- phase 2: GEMM2 [64x1024]@[1024x512]; wave owns 64 cols; 2-deep W2 prefetch
    f32x4 acc2[4][4];
#pragma unroll
    for (int mt = 0; mt < 4; ++mt)
#pragma unroll
        for (int nt = 0; nt < 4; ++nt) acc2[mt][nt] = (f32x4)0.f;
    const short* w2base = w2t + (size_t)(wave * 64 + li) * 1024 + kq * 8;
    bf16x8 wf0[4], wf1[4];
#pragma unroll
    for (int nt = 0; nt < 4; ++nt) wf0[nt] = *(const bf16x8*)(w2base + nt * 16384);
#pragma unroll
    for (int nt = 0; nt < 4; ++nt) wf1[nt] = *(const bf16x8*)(w2base + nt * 16384 + 32);
    for (int ks = 0; ks < 32; ks += 2) {
        bf16x8 xf[4];
#pragma unroll
        for (int mt = 0; mt < 4; ++mt) {
            int m = mt * 16 + li;
            int addr = (m * 2048 + ks * 64 + kq * 16) ^ ((m & 7) << 4);
            xf[mt] = *(bf16x8*)(h1b + addr);
        }
        bf16x8 wfp[4], wfq[4];
#pragma unroll
        for (int nt = 0; nt < 4; ++nt) wfp[nt] = *(const bf16x8*)(w2base + nt * 16384 + (ks + 2) * 32);
#pragma unroll
        for (int nt = 0; nt < 4; ++nt) wfq[nt] = *(const bf16x8*)(w2base + nt * 16384 + (ks + 3) * 32);
#pragma unroll
        for (int nt = 0; nt < 4; ++nt)
#pragma unroll
            for (int mt = 0; mt < 4; ++mt)
                acc2[mt][nt] = __builtin_amdgcn_mfma_f32_16x16x32_bf16(wf0[nt], xf[mt], acc2[mt][nt], 0, 0, 0);
#pragma unroll
        for (int mt = 0; mt < 4; ++mt) {
            int m = mt * 16 + li;
            int addr = (m * 2048 + ks * 64 + 64 + kq * 16) ^ ((m & 7) << 4);
            xf[mt] = *(bf16x8*)(h1b + addr);
        }
#pragma unroll
        for (int nt = 0; nt < 4; ++nt)
#pragma unroll
            for (int mt = 0; mt < 4; ++mt)
                acc2[mt][nt] = __builtin_amdgcn_mfma_f32_16x16x32_bf16(wf1[nt], xf[mt], acc2[mt][nt], 0, 0, 0);
#pragma unroll
        for (int nt = 0; nt < 4; ++nt) { wf0[nt] = wfp[nt]; wf1[nt] = wfq[nt]; }
    }
    __syncthreads();   // all waves done reading h1
    // h2 = relu(acc2 + b2) -> bf16 into h1[0:64KB]
#pragma unroll
    for (int mt = 0; mt < 4; ++mt)
#pragma unroll
        for (int nt = 0; nt < 4; ++nt) {
            int m = mt * 16 + li;
            int nb = wave * 64 + nt * 16 + kq * 4;
            float4 bb = *(const float4*)&b2[nb];
            float v0 = fmaxf(acc2[mt][nt][0] + bb.x, 0.f);
            float v1 = fmaxf(acc2[mt][nt][1] + bb.y, 0.f);
            float v2 = fmaxf(acc2[mt][nt][2] + bb.z, 0.f);
            float v3 = fmaxf(acc2[mt][nt][3] + bb.w, 0.f);
            uint2 pw; pw.x = pack2(v0, v1); pw.y = pack2(v2, v3);
            int addr = (m * 1024 + nb * 2) ^ ((m & 7) << 4);
            *(uint2*)(h1b + addr) = pw;
        }
    __syncthreads();

    // ---- phase 3: GEMM3 [64x512]@[512x48]; wave = (kgroup = wave>>1, mhalf = wave&1)
    int kg = wave >> 1, mhalf = wave & 1;
    f32x4 acc3[2][3];
#pragma unroll
    for (int mt = 0; mt < 2; ++mt)
#pragma unroll
        for (int nt = 0; nt < 3; ++nt) acc3[mt][nt] = (f32x4)0.f;
#pragma unroll
    for (int ks = 0; ks < 4; ++ks) {
        int k0 = kg * 128 + ks * 32;
        bf16x8 xf[2];
#pragma unroll
        for (int mt = 0; mt < 2; ++mt) {
            int m = mhalf * 32 + mt * 16 + li;
            int addr = (m * 1024 + k0 * 2 + kq * 16) ^ ((m & 7) << 4);
            xf[mt] = *(bf16x8*)(h1b + addr);
        }
#pragma unroll
        for (int nt = 0; nt < 3; ++nt) {
            int col = nt * 16 + li;
            bf16x8 wf = *(const bf16x8*)(w3t + col * 512 + k0 + kq * 8);
#pragma unroll
            for (int mt = 0; mt < 2; ++mt)
                acc3[mt][nt] = __builtin_amdgcn_mfma_f32_16x16x32_bf16(wf, xf[mt], acc3[mt][nt], 0, 0, 0);
        }
    }
    float* part = (float*)(h1b + 65536);   // [4 kg][64 m][48 n] f32 = 48KB
#pragma unroll
    for (int mt = 0; mt < 2; ++mt)
#pragma unroll
        for (int nt = 0; nt < 3; ++nt) {
            int m = mhalf * 32 + mt * 16 + li;
            int nb = nt * 16 + kq * 4;
            float4 v = {acc3[mt][nt][0], acc3[mt][nt][1], acc3[mt][nt][2], acc3[mt][nt][3]};
            *(float4*)&part[(kg * 64 + m) * 48 + nb] = v;
        }
    __syncthreads();
    // reduce over 4 k-groups + bias + sigmoid + clip (64*40 = 2560 outputs)
#pragma unroll
    for (int i = 0; i < 5; ++i) {
        int o = t + i * 512;
        int m = o / ODIM, n = o - m * ODIM;
        float s = b3[n];
#pragma unroll
        for (int g = 0; g < 4; ++g) s += part[(g * 64 + m) * 48 + n];
        s = 1.f / (1.f + __expf(-s));
        s = fminf(fmaxf(s, 0.01f), 0.99f);
        out[(size_t)(m0 + m) * ODIM + n] = s;
    }
}

extern "C" void kernel_launch(void* const* d_in, const int* in_sizes, int n_in,
                              void* d_out, int out_size, void* d_ws, size_t ws_size,
                              hipStream_t stream)
{
    const float* x     = (const float*)d_in[0];
    const float* mask  = (const float*)d_in[1];
    const float* w     = (const float*)d_in[2];
    const float* a_src = (const float*)d_in[3];
    const float* a_dst = (const float*)d_in[4];
    const float* bias  = (const float*)d_in[5];
    const float* W1    = (const float*)d_in[6];
    const float* b1    = (const float*)d_in[7];
    const float* W2    = (const float*)d_in[8];
    const float* b2    = (const float*)d_in[9];
    const float* W3    = (const float*)d_in[10];
    const float* b3    = (const float*)d_in[11];
    float* out = (float*)d_out;

    char* p = (char*)d_ws;
    short* hpT = (short*)p;  p += (size_t)BB*NH*FO*NN*2;   // 16.78 MB
    float* asrc = (float*)p; p += (size_t)BB*NH*NN*4;
    float* adst = (float*)p; p += (size_t)BB*NH*NN*4;
    float* rm   = (float*)p; p += (size_t)BB*NH*NN*4;
    float* rr   = (float*)p; p += (size_t)BB*NH*NN*4;
    float* gat  = (float*)p; p += (size_t)BB*NN*FO*4;      // 8.39 MB
    short* w1t  = (short*)p; p += (size_t)HD1*FO*2;
    short* w2t  = (short*)p; p += (size_t)HD2*HD1*2;
    short* w3t  = (short*)p; p += (size_t)48*HD2*2;
    float* wa   = (float*)p; p += 128*4;                   // total ~28.6 MB

    k_wa   <<<1, 64, 0, stream>>>(w, a_src, a_dst, wa);
    k_conv <<<(HD1*FO + HD2*HD1 + 48*HD2)/256, 256, 0, stream>>>(W1, W2, W3, w1t, w2t, w3t);
    k_proj2<<<dim3(NN/64, BB), 256, 0, stream>>>(x, w, bias, wa, hpT, asrc, adst, gat);
    k_stats<<<BB*NH, 256, 0, stream>>>(asrc, adst, rm, rr);
    k_attn2<<<dim3(NN/64, BB), 256, 0, stream>>>(hpT, mask, asrc, rm, rr, adst, gat);
    k_mlp2 <<<BB*NN/64, 512, 139264, stream>>>(gat, w1t, b1, w2t, b2, w3t, b3, out);
}

// Round 6
// 206.879 us; speedup vs baseline: 6.1529x; 1.3212x over previous
//
#include <hip/hip_runtime.h>
#include <math.h>

typedef short bf16x8 __attribute__((ext_vector_type(8)));
typedef float f32x4 __attribute__((ext_vector_type(4)));

#define BB 64
#define NN 512
#define NH 4
#define FI 16
#define FO 64
#define HD1 1024
#define HD2 512
#define ODIM 40

__device__ __forceinline__ unsigned short f2bf(float f) {
    unsigned u = __float_as_uint(f);
    u += 0x7fffu + ((u >> 16) & 1u);        // RNE
    return (unsigned short)(u >> 16);
}
__device__ __forceinline__ unsigned pack2(float a, float b) {
    return (unsigned)f2bf(a) | ((unsigned)f2bf(b) << 16);
}
// async global->LDS, 16B per lane; lds dest = wave-uniform base + lane*16
__device__ __forceinline__ void gload16(const void* g, void* l) {
    __builtin_amdgcn_global_load_lds(
        (const __attribute__((address_space(1))) unsigned int*)g,
        (__attribute__((address_space(3))) unsigned int*)l,
        16, 0, 0);
}

// ---------------- kernel 0: wa[h][i] = sum_o w[h][i][o] * a_{src,dst}[h][o] ----------------
__global__ void k_wa(const float* __restrict__ w, const float* __restrict__ a_src,
                     const float* __restrict__ a_dst, float* __restrict__ wa)
{
    int t = threadIdx.x;      // 0..63 = h*16+i
    int h = t >> 4;
    float s = 0.f, d = 0.f;
    for (int o = 0; o < FO; ++o) {
        float wv = w[t*FO + o];
        s = fmaf(wv, a_src[h*FO + o], s);
        d = fmaf(wv, a_dst[h*FO + o], d);
    }
    wa[t] = s; wa[64 + t] = d;
}

// ---------------- kernel 1: projection -> hpT bf16 (transposed), asrc/adst, gat=bias+skip ----------------
__global__ __launch_bounds__(256) void k_proj2(
    const float* __restrict__ x, const float* __restrict__ w,
    const float* __restrict__ bias, const float* __restrict__ wa,
    short* __restrict__ hpT,           // [B*H][64 o][512 n] bf16
    float* __restrict__ asrc, float* __restrict__ adst,
    float* __restrict__ gat)
{
    __shared__ float xS[64][20];       // padded (rows 80B, 16B-aligned float4 reads)
    __shared__ float gS[NH][64][64];   // 64KB per-head partials
    int b = blockIdx.y;
    int n0 = blockIdx.x * 64;
    int t = threadIdx.x;
    int h = t >> 6, o = t & 63;
    {
        // 64 rows x 16 floats = 256 float4 loads: exactly one per thread
        int n = t >> 2, q = t & 3;
        float4 v = *(const float4*)&x[((size_t)b*NN + n0 + n)*FI + q*4];
        *(float4*)&xS[n][q*4] = v;
    }
    float wreg[16];
#pragma unroll
    for (int i = 0; i < FI; ++i) wreg[i] = w[(h*FI + i)*FO + o];
    __syncthreads();

    size_t hbase = ((size_t)(b*NH + h)*FO + o) * NN + n0;
    for (int nc = 0; nc < 8; ++nc) {
        float acc[8];
#pragma unroll
        for (int k = 0; k < 8; ++k) {
            int n = nc*8 + k;
            float4 a0 = *(const float4*)&xS[n][0];
            float4 a1 = *(const float4*)&xS[n][4];
            float4 a2 = *(const float4*)&xS[n][8];
            float4 a3 = *(const float4*)&xS[n][12];
            float sA = fmaf(a0.x, wreg[0], fmaf(a0.y, wreg[1], fmaf(a0.z, wreg[2], a0.w*wreg[3])));
            float sB = fmaf(a1.x, wreg[4], fmaf(a1.y, wreg[5], fmaf(a1.z, wreg[6], a1.w*wreg[7])));
            float sC = fmaf(a2.x, wreg[8], fmaf(a2.y, wreg[9], fmaf(a2.z, wreg[10], a2.w*wreg[11])));
            float sD = fmaf(a3.x, wreg[12], fmaf(a3.y, wreg[13], fmaf(a3.z, wreg[14], a3.w*wreg[15])));
            float s = (sA + sB) + (sC + sD);
            acc[k] = s;
            gS[h][n][o] = s;
        }
        uint4 p;
        p.x = pack2(acc[0], acc[1]); p.y = pack2(acc[2], acc[3]);
        p.z = pack2(acc[4], acc[5]); p.w = pack2(acc[6], acc[7]);
        *(uint4*)&hpT[hbase + nc*8] = p;
    }
    {
        int n = o;
        float vs = 0.f, vd = 0.f;
#pragma unroll
        for (int i = 0; i < FI; ++i) {
            float xv = xS[n][i];
            vs = fmaf(xv, wa[h*FI + i], vs);
            vd = fmaf(xv, wa[64 + h*FI + i], vd);
        }
        asrc[(size_t)(b*NH + h)*NN + n0 + n] = vs;
        adst[(size_t)(b*NH + h)*NN + n0 + n] = vd;
    }
    __syncthreads();
#pragma unroll
    for (int r = 0; r < 16; ++r) {
        int idx = t + r*256;
        int n = idx >> 6, oo = idx & 63;
        float g = bias[oo] + ((gS[0][n][oo] + gS[1][n][oo]) + (gS[2][n][oo] + gS[3][n][oo]));
        gat[((size_t)b*NN + n0 + n)*FO + oo] = g;
    }
}

// ---------------- kernel 2: per-row softmax stats (max, 1/sumexp), 1 row/thread ----------------
__global__ __launch_bounds__(256) void k_stats(
    const float* __restrict__ asrc, const float* __restrict__ adst,
    float* __restrict__ rm, float* __restrict__ rr)
{
    int bh = blockIdx.x;              // b*NH + h
    __shared__ float d[NN];
    int t = threadIdx.x;
    for (int j = t; j < NN; j += 256) d[j] = adst[bh * NN + j];
    __syncthreads();
    int i = blockIdx.y * 256 + t;
    float s = asrc[bh * NN + i];
    float m = -INFINITY;
    for (int j = 0; j < NN; ++j) {
        float v = s * d[j];
        v = fmaxf(v, 0.2f * v);
        m = fmaxf(m, v);
    }
    float sum = 0.f;
    for (int j = 0; j < NN; ++j) {
        float v = s * d[j];
        v = fmaxf(v, 0.2f * v);
        sum += __expf(v - m);
    }
    rm[bh * NN + i] = m;
    rr[bh * NN + i] = 1.0f / sum;     // mask applied AFTER softmax
}

// ---------------- kernel 3: MFMA attention, V tile staged via global_load_lds ----------------
__global__ __launch_bounds__(256) void k_attn2(
    const short* __restrict__ hpT, const float* __restrict__ mask,
    const float* __restrict__ asrc, const float* __restrict__ rm, const float* __restrict__ rr,
    const float* __restrict__ adst,
    float* __restrict__ gat)
{
    __shared__ float dS[NH*NN];       // 8KB
    __shared__ char vts[16384];       // V tile [256 (h,o) rows][32 j] bf16, slot-swizzled
    int b = blockIdx.y;
    int i0blk = blockIdx.x * 64;
    int t = threadIdx.x;
#pragma unroll
    for (int r = 0; r < 8; ++r) {
        int idx = t + r*256;
        dS[idx] = adst[(size_t)b*(NH*NN) + idx];
    }
    int wv = t >> 6, lane = t & 63;
    int li = lane & 15, kq = lane >> 4;
    int i = i0blk + wv*16 + li;
    float s[NH], m[NH], rcp[NH];
#pragma unroll
    for (int h = 0; h < NH; ++h) {
        size_t ix = (size_t)(b*NH + h)*NN + i;
        s[h] = asrc[ix]; m[h] = rm[ix]; rcp[h] = rr[ix];
    }
    __syncthreads();
    f32x4 acc[4];
#pragma unroll
    for (int ot = 0; ot < 4; ++ot) acc[ot] = (f32x4)0.f;

    const float* mrow = &mask[((size_t)b*NN + i)*NN];
    for (int jt = 0; jt < 16; ++jt) {
        int j0 = jt*32;
        // stage V tile: row = h*64+o (64B = 4 slots of 16B), pre-swizzled source
#pragma unroll
        for (int q = 0; q < 4; ++q) {
            int flatB = wv*4096 + q*1024 + lane*16;
            int row = flatB >> 6;
            int slotS = ((flatB >> 4) & 3) ^ ((row >> 1) & 3);
            const short* src = hpT + ((size_t)b*256 + row)*NN + j0 + slotS*8;
            gload16(src, vts + wv*4096 + q*1024);
        }
        __syncthreads();   // drains vmcnt -> tile visible
        float4 mk0 = *(const float4*)&mrow[j0 + kq*8];
        float4 mk1 = *(const float4*)&mrow[j0 + kq*8 + 4];
        float mk[8] = {mk0.x, mk0.y, mk0.z, mk0.w, mk1.x, mk1.y, mk1.z, mk1.w};
#pragma unroll
        for (int h = 0; h < NH; ++h) {
            float4 d0 = *(const float4*)&dS[h*NN + j0 + kq*8];
            float4 d1 = *(const float4*)&dS[h*NN + j0 + kq*8 + 4];
            float dv[8] = {d0.x,d0.y,d0.z,d0.w,d1.x,d1.y,d1.z,d1.w};
            union { bf16x8 v; unsigned u[4]; } pf;
#pragma unroll
            for (int q = 0; q < 4; ++q) {
                float v0 = s[h]*dv[2*q];   v0 = fmaxf(v0, 0.2f*v0);
                float v1 = s[h]*dv[2*q+1]; v1 = fmaxf(v1, 0.2f*v1);
                float e0 = __expf(v0 - m[h]) * rcp[h] * mk[2*q];
                float e1 = __expf(v1 - m[h]) * rcp[h] * mk[2*q+1];
                pf.u[q] = pack2(e0, e1);
            }
#pragma unroll
            for (int ot = 0; ot < 4; ++ot) {
                int row = h*64 + ot*16 + li;
                int slot = kq ^ ((row >> 1) & 3);
                bf16x8 vf = *(bf16x8*)(vts + row*64 + slot*16);
                acc[ot] = __builtin_amdgcn_mfma_f32_16x16x32_bf16(pf.v, vf, acc[ot], 0, 0, 0);
            }
        }
        __syncthreads();   // all reads done before next stage overwrites
    }
#pragma unroll
    for (int ot = 0; ot < 4; ++ot) {
#pragma unroll
        for (int g = 0; g < 4; ++g) {
            int ii = i0blk + wv*16 + kq*4 + g;
            int oo = ot*16 + li;
            size_t ix = ((size_t)b*NN + ii)*FO + oo;
            gat[ix] += acc[ot][g];
        }
    }
}

// ---------------- kernel 4a: convert MLP weights to bf16, transposed (n-major) ----------------
__global__ __launch_bounds__(256) void k_conv(
    const float* __restrict__ W1, const float* __restrict__ W2, const float* __restrict__ W3,
    short* __restrict__ w1t, short* __restrict__ w2t, short* __restrict__ w3t)
{
    int idx = blockIdx.x * 256 + threadIdx.x;
    if (idx < HD1*FO) {
        int n = idx >> 6, k = idx & 63;
        w1t[idx] = (short)f2bf(W1[k*HD1 + n]);
    } else if (idx < HD1*FO + HD2*HD1) {
        int i2 = idx - HD1*FO;
        int n = i2 >> 10, k = i2 & 1023;
        w2t[i2] = (short)f2bf(W2[k*HD2 + n]);
    } else if (idx < HD1*FO + HD2*HD1 + 48*HD2) {
        int i3 = idx - (HD1*FO + HD2*HD1);
        int n = i3 >> 9, k = i3 & 511;
        w3t[i3] = (short)(n < ODIM ? f2bf(W3[k*ODIM + n]) : 0);
    }
}

// ---------------- kernel 4b: fused MFMA MLP; GEMM2 streams W2 through LDS ----------------
// LDS: h1 [64][1024] bf16 swizzled (128KB) + w2s [512 n][32 k] bf16 (32KB) = 160KB.
// a0 (8KB) aliases w2s; h2 aliases h1[0:64KB]; GEMM3 partials at h1+64KB.
__global__ __launch_bounds__(512, 2) void k_mlp2(
    const float* __restrict__ gat,
    const short* __restrict__ w1t, const float* __restrict__ b1,
    const short* __restrict__ w2t, const float* __restrict__ b2,
    const short* __restrict__ w3t, const float* __restrict__ b3,
    float* __restrict__ out)
{
    extern __shared__ char smem[];
    char* h1b = smem;                 // 131072 B
    char* w2s = smem + 131072;        // 32768 B (a0 aliases first 8KB)
    char* a0b = w2s;
    int t = threadIdx.x;
    int lane = t & 63, wave = t >> 6;
    int li = lane & 15, kq = lane >> 4;
    int m0 = blockIdx.x * 64;

    // ---- phase 0: relu(gat) -> bf16 -> a0 [64][64], swizzled
    {
        int row = t >> 3, c0 = (t & 7) * 8;
        const float4* g = (const float4*)&gat[(size_t)(m0 + row) * FO + c0];
        float4 v0 = g[0], v1 = g[1];
        uint4 p;
        p.x = pack2(fmaxf(v0.x, 0.f), fmaxf(v0.y, 0.f));
        p.y = pack2(fmaxf(v0.z, 0.f), fmaxf(v0.w, 0.f));
        p.z = pack2(fmaxf(v1.x, 0.f), fmaxf(v1.y, 0.f));
        p.w = pack2(fmaxf(v1.z, 0.f), fmaxf(v1.w, 0.f));
        int addr = (row * 128 + c0 * 2) ^ ((row & 7) << 4);
        *(uint4*)(a0b + addr) = p;
    }
    __syncthreads();

    // ---- phase 1: GEMM1 [64x64]@[64x1024] -> relu -> bf16 h1; wave owns 128 cols
    for (int c = 0; c < 2; ++c) {
        int n0 = wave * 128 + c * 64;
        f32x4 acc[4][4];
#pragma unroll
        for (int mt = 0; mt < 4; ++mt)
#pragma unroll
            for (int nt = 0; nt < 4; ++nt) acc[mt][nt] = (f32x4)0.f;
#pragma unroll
        for (int ks = 0; ks < 2; ++ks) {
            int k0 = ks * 32;
            bf16x8 xf[4];
#pragma unroll
            for (int mt = 0; mt < 4; ++mt) {
                int row = mt * 16 + li;
                int addr = (row * 128 + k0 * 2 + kq * 16) ^ ((row & 7) << 4);
                xf[mt] = *(bf16x8*)(a0b + addr);
            }
#pragma unroll
            for (int nt = 0; nt < 4; ++nt) {
                int col = n0 + nt * 16 + li;
                bf16x8 wf = *(const bf16x8*)(w1t + col * 64 + k0 + kq * 8);
#pragma unroll
                for (int mt = 0; mt < 4; ++mt)
                    acc[mt][nt] = __builtin_amdgcn_mfma_f32_16x16x32_bf16(wf, xf[mt], acc[mt][nt], 0, 0, 0);
            }
        }
#pragma unroll
        for (int mt = 0; mt < 4; ++mt)
#pragma unroll
            for (int nt = 0; nt < 4; ++nt) {
                int m = mt * 16 + li;
                int nb = n0 + nt * 16 + kq * 4;
                float4 bb = *(const float4*)&b1[nb];
                float v0 = fmaxf(acc[mt][nt][0] + bb.x, 0.f);
                float v1 = fmaxf(acc[mt][nt][1] + bb.y, 0.f);
                float v2 = fmaxf(acc[mt][nt][2] + bb.z, 0.f);
                float v3 = fmaxf(acc[mt][nt][3] + bb.w, 0.f);
                uint2 pw; pw.x = pack2(v0, v1); pw.y = pack2(v2, v3);
                int addr = (m * 2048 + nb * 2) ^ ((m & 7) << 4);
                *(uint2*)(h1b + addr) = pw;
            }
    }
    __syncthreads();

    // ---- phase 2: GEMM2 [64x1024]@[1024x512]; W2 k-slice staged in LDS per step
    f32x4 acc2[4][4];
#pragma unroll
    for (int mt = 0; mt < 4; ++mt)
#pragma unroll
        for (int nt = 0; nt < 4; ++nt) acc2[mt][nt] = (f32x4)0.f;
    for (int ks = 0; ks < 32; ++ks) {
        int k0 = ks * 32;
        // stage w2s [512 n][32 k] (64B rows, 4 slots), pre-swizzled source
#pragma unroll
        for (int q = 0; q < 4; ++q) {
            int flatB = wave * 4096 + q * 1024 + lane * 16;
            int n = flatB >> 6;
            int slotS = ((flatB >> 4) & 3) ^ ((n >> 1) & 3);
            const short* src = w2t + (size_t)n * 1024 + k0 + slotS * 8;
            gload16(src, w2s + wave * 4096 + q * 1024);
        }
        __syncthreads();   // drain vmcnt -> tile visible
        bf16x8 xf[4], wf[4];
#pragma unroll
        for (int mt = 0; mt < 4; ++mt) {
            int m = mt * 16 + li;
            int addr = (m * 2048 + k0 * 2 + kq * 16) ^ ((m & 7) << 4);
            xf[mt] = *(bf16x8*)(h1b + addr);
        }
#pragma unroll
        for (int nt = 0; nt < 4; ++nt) {
            int n = wave * 64 + nt * 16 + li;
            int slot = kq ^ ((n >> 1) & 3);
            wf[nt] = *(bf16x8*)(w2s + n * 64 + slot * 16);
        }
#pragma unroll
        for (int nt = 0; nt < 4; ++nt)
#pragma unroll
            for (int mt = 0; mt < 4; ++mt)
                acc2[mt][nt] = __builtin_amdgcn_mfma_f32_16x16x32_bf16(wf[nt], xf[mt], acc2[mt][nt], 0, 0, 0);
        __syncthreads();   // reads done before next stage overwrites
    }
    // h2 = relu(acc2 + b2) -> bf16 into h1[0:64KB]
#pragma unroll
    for (int mt = 0; mt < 4; ++mt)
#pragma unroll
        for (int nt = 0; nt < 4; ++nt) {
            int m = mt * 16 + li;
            int nb = wave * 64 + nt * 16 + kq * 4;
            float4 bb = *(const float4*)&b2[nb];
            float v0 = fmaxf(acc2[mt][nt][0] + bb.x, 0.f);
            float v1 = fmaxf(acc2[mt][nt][1] + bb.y, 0.f);
            float v2 = fmaxf(acc2[mt][nt][2] + bb.z, 0.f);
            float v3 = fmaxf(acc2[mt][nt][3] + bb.w, 0.f);
            uint2 pw; pw.x = pack2(v0, v1); pw.y = pack2(v2, v3);
            int addr = (m * 1024 + nb * 2) ^ ((m & 7) << 4);
            *(uint2*)(h1b + addr) = pw;
        }
    __syncthreads();

    // ---- phase 3: GEMM3 [64x512]@[512x48]; wave = (kgroup = wave>>1, mhalf = wave&1)
    int kg = wave >> 1, mhalf = wave & 1;
    f32x4 acc3[2][3];
#pragma unroll
    for (int mt = 0; mt < 2; ++mt)
#pragma unroll
        for (int nt = 0; nt < 3; ++nt) acc3[mt][nt] = (f32x4)0.f;
#pragma unroll
    for (int ks = 0; ks < 4; ++ks) {
        int k0 = kg * 128 + ks * 32;
        bf16x8 xf[2];
#pragma unroll
        for (int mt = 0; mt < 2; ++mt) {
            int m = mhalf * 32 + mt * 16 + li;
            int addr = (m * 1024 + k0 * 2 + kq * 16) ^ ((m & 7) << 4);
            xf[mt] = *(bf16x8*)(h1b + addr);
        }
#pragma unroll
        for (int nt = 0; nt < 3; ++nt) {
            int col = nt * 16 + li;
            bf16x8 wf = *(const bf16x8*)(w3t + col * 512 + k0 + kq * 8);
#pragma unroll
            for (int mt = 0; mt < 2; ++mt)
                acc3[mt][nt] = __builtin_amdgcn_mfma_f32_16x16x32_bf16(wf, xf[mt], acc3[mt][nt], 0, 0, 0);
        }
    }
    float* part = (float*)(h1b + 65536);   // [4 kg][64 m][48 n] f32 = 48KB
#pragma unroll
    for (int mt = 0; mt < 2; ++mt)
#pragma unroll
        for (int nt = 0; nt < 3; ++nt) {
            int m = mhalf * 32 + mt * 16 + li;
            int nb = nt * 16 + kq * 4;
            float4 v = {acc3[mt][nt][0], acc3[mt][nt][1], acc3[mt][nt][2], acc3[mt][nt][3]};
            *(float4*)&part[(kg * 64 + m) * 48 + nb] = v;
        }
    __syncthreads();
    // reduce over 4 k-groups + bias + sigmoid + clip (64*40 = 2560 outputs)
#pragma unroll
    for (int i = 0; i < 5; ++i) {
        int o = t + i * 512;
        int m = o / ODIM, n = o - m * ODIM;
        float s = b3[n];
#pragma unroll
        for (int g = 0; g < 4; ++g) s += part[(g * 64 + m) * 48 + n];
        s = 1.f / (1.f + __expf(-s));
        s = fminf(fmaxf(s, 0.01f), 0.99f);
        out[(size_t)(m0 + m) * ODIM + n] = s;
    }
}

extern "C" void kernel_launch(void* const* d_in, const int* in_sizes, int n_in,
                              void* d_out, int out_size, void* d_ws, size_t ws_size,
                              hipStream_t stream)
{
    const float* x     = (const float*)d_in[0];
    const float* mask  = (const float*)d_in[1];
    const float* w     = (const float*)d_in[2];
    const float* a_src = (const float*)d_in[3];
    const float* a_dst = (const float*)d_in[4];
    const float* bias  = (const float*)d_in[5];
    const float* W1    = (const float*)d_in[6];
    const float* b1    = (const float*)d_in[7];
    const float* W2    = (const float*)d_in[8];
    const float* b2    = (const float*)d_in[9];
    const float* W3    = (const float*)d_in[10];
    const float* b3    = (const float*)d_in[11];
    float* out = (float*)d_out;

    char* p = (char*)d_ws;
    short* hpT = (short*)p;  p += (size_t)BB*NH*FO*NN*2;   // 16.78 MB
    float* asrc = (float*)p; p += (size_t)BB*NH*NN*4;
    float* adst = (float*)p; p += (size_t)BB*NH*NN*4;
    float* rm   = (float*)p; p += (size_t)BB*NH*NN*4;
    float* rr   = (float*)p; p += (size_t)BB*NH*NN*4;
    float* gat  = (float*)p; p += (size_t)BB*NN*FO*4;      // 8.39 MB
    short* w1t  = (short*)p; p += (size_t)HD1*FO*2;
    short* w2t  = (short*)p; p += (size_t)HD2*HD1*2;
    short* w3t  = (short*)p; p += (size_t)48*HD2*2;
    float* wa   = (float*)p; p += 128*4;                   // total ~28.6 MB

    k_wa   <<<1, 64, 0, stream>>>(w, a_src, a_dst, wa);
    k_conv <<<(HD1*FO + HD2*HD1 + 48*HD2)/256, 256, 0, stream>>>(W1, W2, W3, w1t, w2t, w3t);
    k_proj2<<<dim3(NN/64, BB), 256, 0, stream>>>(x, w, bias, wa, hpT, asrc, adst, gat);
    k_stats<<<dim3(BB*NH, 2), 256, 0, stream>>>(asrc, adst, rm, rr);
    k_attn2<<<dim3(NN/64, BB), 256, 0, stream>>>(hpT, mask, asrc, rm, rr, adst, gat);
    k_mlp2 <<<BB*NN/64, 512, 163840, stream>>>(gat, w1t, b1, w2t, b2, w3t, b3, out);
}